// Round 7
// baseline (384.844 us; speedup 1.0000x reference)
//
#include <hip/hip_runtime.h>

typedef unsigned short u16;
typedef unsigned int u32;
typedef short v8s __attribute__((ext_vector_type(8)));
typedef float v4f __attribute__((ext_vector_type(4)));
typedef float v16f __attribute__((ext_vector_type(16)));

#define MFMA16(a, b, c) __builtin_amdgcn_mfma_f32_16x16x32_bf16((a), (b), (c), 0, 0, 0)
#define MFMA32(a, b, c) __builtin_amdgcn_mfma_f32_32x32x16_bf16((a), (b), (c), 0, 0, 0)

static __device__ __forceinline__ u16 f2bf(float f) {
    u32 u = __float_as_uint(f);
    u += 0x7fffu + ((u >> 16) & 1u);   // RNE
    return (u16)(u >> 16);
}

// async global->LDS, 16B per lane. LDS dest must be wave-uniform base + lane*16.
static __device__ __forceinline__ void gl2lds(const u16* g, u16* l) {
    __builtin_amdgcn_global_load_lds(
        (const __attribute__((address_space(1))) void*)g,
        (__attribute__((address_space(3))) void*)l, 16, 0, 0);
}

// ---------------------------------------------------------------------------
// prep: fp32 weights -> bf16 (Wqkv packed [1536][512], Wp [512][512]), bias pack
// ---------------------------------------------------------------------------
__global__ __launch_bounds__(256) void prep_kernel(
    const float* __restrict__ wq, const float* __restrict__ wk,
    const float* __restrict__ wv, const float* __restrict__ wp,
    const float* __restrict__ bq, const float* __restrict__ bk,
    const float* __restrict__ bv,
    u16* __restrict__ Wqkv, u16* __restrict__ Wp, float* __restrict__ bqkv) {
    int id = blockIdx.x * 256 + threadIdx.x;   // 0 .. 1048575
    float v;
    if (id < 262144)       v = wq[id];
    else if (id < 524288)  v = wk[id - 262144];
    else if (id < 786432)  v = wv[id - 524288];
    else                   v = wp[id - 786432];
    if (id < 786432) Wqkv[id] = f2bf(v);
    else             Wp[id - 786432] = f2bf(v);
    if (id < 1536) {
        float b = (id < 512) ? bq[id] : (id < 1024 ? bk[id - 512] : bv[id - 1024]);
        bqkv[id] = b;
    }
}

// ---------------------------------------------------------------------------
// GroupNorm pass 1: per (b,g) mean & rsigma over 16 ch x 1024 spatial
// ---------------------------------------------------------------------------
__global__ __launch_bounds__(256) void gn_stats(const float* __restrict__ x,
                                                float2* __restrict__ stats) {
    int g = blockIdx.x, b = blockIdx.y;
    const float4* x4 = (const float4*)x + (size_t)(b * 512 + g * 16) * 256;
    float s = 0.f, s2 = 0.f;
    for (int i = threadIdx.x; i < 4096; i += 256) {
        float4 v = x4[i];
        s  += v.x + v.y + v.z + v.w;
        s2 += v.x * v.x + v.y * v.y + v.z * v.z + v.w * v.w;
    }
    #pragma unroll
    for (int d = 1; d < 64; d <<= 1) { s += __shfl_xor(s, d); s2 += __shfl_xor(s2, d); }
    __shared__ float red1[4], red2[4];
    int w = threadIdx.x >> 6;
    if ((threadIdx.x & 63) == 0) { red1[w] = s; red2[w] = s2; }
    __syncthreads();
    if (threadIdx.x == 0) {
        s = red1[0] + red1[1] + red1[2] + red1[3];
        s2 = red2[0] + red2[1] + red2[2] + red2[3];
        float mu = s * (1.0f / 16384.0f);
        float var = s2 * (1.0f / 16384.0f) - mu * mu;
        stats[b * 32 + g] = make_float2(mu, rsqrtf(var + 1e-5f));
    }
}

// ---------------------------------------------------------------------------
// GroupNorm pass 2 + transpose: x[b,c,s] fp32 -> h[b*1024+s][c] bf16 (token-major)
// ---------------------------------------------------------------------------
__global__ __launch_bounds__(256) void gn_apply(
    const float* __restrict__ x, const float2* __restrict__ stats,
    const float* __restrict__ gnw, const float* __restrict__ gnb,
    u16* __restrict__ h) {
    int st = blockIdx.x, b = blockIdx.y;
    int s0 = st * 64;
    __shared__ float smu[32], srs[32], sw[512], sbv[512];
    __shared__ alignas(16) u16 hs[64][520];
    int t = threadIdx.x;
    if (t < 32) { float2 v = stats[b * 32 + t]; smu[t] = v.x; srs[t] = v.y; }
    sw[t] = gnw[t]; sw[t + 256] = gnw[t + 256];
    sbv[t] = gnb[t]; sbv[t + 256] = gnb[t + 256];
    __syncthreads();
    #pragma unroll 4
    for (int it = 0; it < 32; ++it) {
        int id = it * 256 + t;
        int c = id >> 4, f4 = id & 15;
        float4 v = ((const float4*)x)[(size_t)(b * 512 + c) * 256 + (s0 >> 2) + f4];
        int g = c >> 4;
        float mu = smu[g], r = srs[g], wgt = sw[c], bia = sbv[c];
        hs[f4 * 4 + 0][c] = f2bf((v.x - mu) * r * wgt + bia);
        hs[f4 * 4 + 1][c] = f2bf((v.y - mu) * r * wgt + bia);
        hs[f4 * 4 + 2][c] = f2bf((v.z - mu) * r * wgt + bia);
        hs[f4 * 4 + 3][c] = f2bf((v.w - mu) * r * wgt + bia);
    }
    __syncthreads();
    int lane = t & 63, wrow = t >> 6;
    #pragma unroll 4
    for (int it = 0; it < 16; ++it) {
        int s = it * 4 + wrow;
        float4 vv = *(const float4*)&hs[s][lane * 8];
        *((float4*)h + (size_t)(b * 1024 + s0 + s) * 64 + lane) = vv;
    }
}

// ---------------------------------------------------------------------------
// QKV GEMM, BK=64, double-buffered counted-vmcnt K-loop (round-6, passed).
// Q: token-major, pre-scaled by 512^-0.5.
// K: per-(batch, 16-key tile) image [16 key][512 ch] (8192 u16); 16B blocks
//    (64/row) XOR-swizzled by (key&7).
// V: per-tile image of 64B PAIR-ROWS: row p=ch>>1 holds 4 16B blocks
//    (ch&1, key-half) XOR-swizzled by (p&3) — keeps the 4-deep bank spread
//    at 16-key tile granularity. Images copied verbatim to LDS by flash_attn.
// ---------------------------------------------------------------------------
__global__ __launch_bounds__(256, 2) void gemm_qkv(
    const u16* __restrict__ h, const u16* __restrict__ Wqkv,
    const float* __restrict__ bqkv,
    u16* __restrict__ Qo, u16* __restrict__ Ko, u16* __restrict__ Vo) {
    int n0 = blockIdx.x * 128, m0 = blockIdx.y * 128;
    __shared__ alignas(16) char ldsb[65536];
    u16* As = (u16*)ldsb;             // [2][128][64]  32 KB
    u16* Bs = (u16*)(ldsb + 32768);   // [2][128][64]  32 KB
    u16* Tr = (u16*)ldsb;             // [128][136] epilogue overlay
    int t = threadIdx.x, w = t >> 6, l = t & 63;
    int lane16 = l & 15, quad = l >> 4;
    int wm = w & 1, wn = w >> 1;
    v4f acc[4][4] = {};

#define STAGE_QKV(buf, k0)                                                     \
    {                                                                          \
        _Pragma("unroll")                                                      \
        for (int i_ = 0; i_ < 4; ++i_) {                                       \
            int id_ = i_ * 256 + t, row_ = id_ >> 3, c_ = id_ & 7;             \
            int sc_ = c_ ^ (row_ & 7);                                         \
            gl2lds(&h[(size_t)(m0 + row_) * 512 + (k0) + sc_ * 8],             \
                   &As[(buf) * 8192 + row_ * 64 + c_ * 8]);                    \
            gl2lds(&Wqkv[(size_t)(n0 + row_) * 512 + (k0) + sc_ * 8],          \
                   &Bs[(buf) * 8192 + row_ * 64 + c_ * 8]);                    \
        }                                                                      \
    }

    STAGE_QKV(0, 0);
    STAGE_QKV(1, 64);
    asm volatile("s_waitcnt vmcnt(8)" ::: "memory");
    __builtin_amdgcn_s_barrier();
    __builtin_amdgcn_sched_barrier(0);

    for (int tt = 0; tt < 8; ++tt) {
        int cb = (tt & 1) * 8192;
        #pragma unroll
        for (int hh = 0; hh < 2; ++hh) {
            v8s af[4], bf[4];
            #pragma unroll
            for (int i = 0; i < 4; ++i) {
                int row = wm * 64 + i * 16 + lane16;
                af[i] = *(const v8s*)&As[cb + row * 64 +
                                         (((hh * 4 + quad) ^ (lane16 & 7)) * 8)];
            }
            #pragma unroll
            for (int j = 0; j < 4; ++j) {
                int row = wn * 64 + j * 16 + lane16;
                bf[j] = *(const v8s*)&Bs[cb + row * 64 +
                                         (((hh * 4 + quad) ^ (lane16 & 7)) * 8)];
            }
            #pragma unroll
            for (int i = 0; i < 4; ++i)
                #pragma unroll
                for (int j = 0; j < 4; ++j)
                    acc[i][j] = MFMA16(af[i], bf[j], acc[i][j]);
        }
        __builtin_amdgcn_s_barrier();              // all readers of buf done
        __builtin_amdgcn_sched_barrier(0);
        if (tt + 2 < 8) {
            STAGE_QKV(tt & 1, (tt + 2) * 64);      // refill freed buffer
            asm volatile("s_waitcnt vmcnt(8)" ::: "memory");   // L(t+1) landed
        } else {
            asm volatile("s_waitcnt vmcnt(0)" ::: "memory");   // tail drain
        }
        __builtin_amdgcn_s_barrier();              // everyone's next buf ready
        __builtin_amdgcn_sched_barrier(0);
    }
#undef STAGE_QKV

    float bias[4];
    #pragma unroll
    for (int j = 0; j < 4; ++j) bias[j] = bqkv[n0 + wn * 64 + j * 16 + lane16];

    if (n0 < 1024) {
        // Q or K: stage [token][channel] tile in LDS (Tr overlays As/Bs)
        const float qscale = (n0 < 512) ? 0.04419417382415922f : 1.0f;
        #pragma unroll
        for (int i = 0; i < 4; ++i)
            #pragma unroll
            for (int j = 0; j < 4; ++j)
                #pragma unroll
                for (int r = 0; r < 4; ++r) {
                    int row = wm * 64 + i * 16 + quad * 4 + r;
                    int col = wn * 64 + j * 16 + lane16;
                    Tr[row * 136 + col] = f2bf((acc[i][j][r] + bias[j]) * qscale);
                }
        __syncthreads();
        if (n0 < 512) {
            #pragma unroll
            for (int it = 0; it < 8; ++it) {
                int id = it * 256 + t, row = id >> 4, ch = id & 15;
                *(float4*)&Qo[(size_t)(m0 + row) * 512 + n0 + ch * 8] =
                    *(const float4*)&Tr[row * 136 + ch * 8];
            }
        } else {
            int c0 = n0 - 512, b = m0 >> 10, sb = m0 & 1023;
            #pragma unroll
            for (int it = 0; it < 8; ++it) {
                int id = it * 256 + t, row = id >> 4, ch = id & 15;
                int s = sb + row, kt = s >> 4, key = s & 15;      // 16-key tiles
                int kb = ((c0 + ch * 8) >> 3) ^ (key & 7);        // XOR swizzle
                *(float4*)&Ko[((size_t)(b * 64 + kt)) * 8192 + key * 512 + kb * 8] =
                    *(const float4*)&Tr[row * 136 + ch * 8];
            }
        }
    } else {
        // V: stage TRANSPOSED [channel][token] in LDS
        #pragma unroll
        for (int i = 0; i < 4; ++i)
            #pragma unroll
            for (int j = 0; j < 4; ++j)
                #pragma unroll
                for (int r = 0; r < 4; ++r) {
                    int row = wm * 64 + i * 16 + quad * 4 + r;
                    int col = wn * 64 + j * 16 + lane16;
                    Tr[col * 136 + row] = f2bf(acc[i][j][r] + bias[j]);
                }
        __syncthreads();
        int c0 = n0 - 1024, b = m0 >> 10, sb = m0 & 1023;
        #pragma unroll
        for (int it = 0; it < 8; ++it) {
            int id = it * 256 + t, c = id >> 4, ch8 = id & 15;
            int key0 = sb + ch8 * 8;                  // 8 consecutive keys
            int kt = key0 >> 4;                       // 16-key tiles
            int kb1 = (key0 >> 3) & 1;                // key half within tile
            int ch = c0 + c;
            int p = ch >> 1;                          // 64B pair-row
            int blk = ((ch & 1) * 2 + kb1) ^ (p & 3); // 4-block XOR swizzle
            *(float4*)&Vo[((size_t)(b * 64 + kt)) * 8192 + p * 32 + blk * 8] =
                *(const float4*)&Tr[c * 136 + ch8 * 8];
        }
    }
}

// ---------------------------------------------------------------------------
// Flash attention v8: CO-RESIDENCY restructure of the proven v3 schedule.
// 16-key tiles, 6-wave (384-thr) blocks, LDS 69.9 KB -> 2 blocks/CU
// (12 waves/CU): one block's barrier/vmcnt drain overlaps the sibling's
// compute — attacks the ~50% unattributed stall at 1-block occupancy.
// ALL per-FLOP rates preserved from v3:
//  Waves 0-1 (producers, qs=w): 32q x 16keys via dual Q-frag sets (each K
//    B-read feeds 2 MFMAs — same K-byte reuse as v3). exp() -> P image
//    [64 q][16 k] (2KB, double-buffered) + l partials (full per-q sums now,
//    single lsum[64]).
//  Waves 2-5 (consumers, (qs2,chh)): PV via 32x32x16, one 16-key chunk per
//    tile (8 MFMA32/wave/tile), V from 64B pair-row image (4-block XOR).
// Staging: K+V 32KB/tile split over 6 waves via strided unit loop.
// One barrier per tile; K/V/P double-buffered; consumers lag by 1 tile.
// ---------------------------------------------------------------------------
__global__ __launch_bounds__(384, 2) void flash_attn(
    const u16* __restrict__ Q, const u16* __restrict__ Kt,
    const u16* __restrict__ Vt, u16* __restrict__ O) {
    int idx = blockIdx.x;
    int xcd = idx & 7, j = idx >> 3;          // XCD-aware: 4 batches per XCD
    int bz = xcd * 4 + (j >> 4);
    int qb = j & 15;                          // 64-query block

    __shared__ alignas(16) char lds[69888];
    u16*   KsB  = (u16*)lds;                  // [2][16][512]   32 KB
    u16*   VsB  = (u16*)(lds + 32768);        // [2][256 pair-rows]  32 KB
    u16*   Pb   = (u16*)(lds + 65536);        // [2][64][16]     4 KB
    float* lsum = (float*)(lds + 69632);      // [64]          256 B

    int t = threadIdx.x, w = t >> 6, l = t & 63;
    int lane16 = l & 15, quad = l >> 4;
    int s5 = l >> 5, l31 = l & 31;

    const u16* Kb = Kt + (size_t)bz * 64 * 8192;
    const u16* Vb = Vt + (size_t)bz * 64 * 8192;

    // prologue: stage K tile 0 (16 KB = 16 1KB units over 6 waves)
    for (int u = w; u < 16; u += 6)
        gl2lds(&Kb[u * 512 + l * 8], &KsB[u * 512 + l * 8]);
    __syncthreads();

    if (w < 2) {
        // ================= PRODUCER (32q x 16k, dual Q-frag sets) ==========
        int qs = w;
        int qrow = bz * 1024 + qb * 64 + qs * 32 + lane16;
        v8s qf0[16], qf1[16];
        #pragma unroll
        for (int kk = 0; kk < 16; ++kk) {
            qf0[kk] = *(const v8s*)&Q[(size_t)qrow * 512 + kk * 32 + quad * 8];
            qf1[kk] = *(const v8s*)&Q[(size_t)(qrow + 16) * 512 + kk * 32 + quad * 8];
        }
        v4f li0 = {}, li1 = {};
        int key = lane16;
        int krowoff = key * 512;
        int kswz = lane16 & 7;

        for (int kt = 0; kt <= 64; ++kt) {
            if (kt + 1 < 64) {
                u16* kd = KsB + ((kt + 1) & 1) * 8192;
                const u16* ks = Kb + (size_t)(kt + 1) * 8192;
                for (int u = w; u < 16; u += 6)
                    gl2lds(&ks[u * 512 + l * 8], &kd[u * 512 + l * 8]);
            }
            if (kt < 64) {
                u16* vd = VsB + (kt & 1) * 8192;
                const u16* vs = Vb + (size_t)kt * 8192;
                for (int u = w; u < 16; u += 6)
                    gl2lds(&vs[u * 512 + l * 8], &vd[u * 512 + l * 8]);
                const u16* KsT = KsB + (kt & 1) * 8192;
                u16* Pt = Pb + (kt & 1) * 1024;
                v4f sA = {}, sB = {};
                #pragma unroll
                for (int kk = 0; kk < 16; ++kk) {
                    v8s b = *(const v8s*)&KsT[krowoff + (((kk * 4 + quad) ^ kswz) * 8)];
                    sA = MFMA16(qf0[kk], b, sA);
                    sB = MFMA16(qf1[kk], b, sB);
                }
                #pragma unroll
                for (int r = 0; r < 4; ++r) {
                    float p0 = __expf(sA[r]), p1 = __expf(sB[r]);
                    li0[r] += p0; li1[r] += p1;
                    int q0 = qs * 32 + quad * 4 + r, q1 = q0 + 16;
                    Pt[q0 * 16 + (((key >> 3) ^ ((q0 >> 1) & 1)) * 8) + (key & 7)] = f2bf(p0);
                    Pt[q1 * 16 + (((key >> 3) ^ ((q1 >> 1) & 1)) * 8) + (key & 7)] = f2bf(p1);
                }
            }
            __syncthreads();
        }
        // reduce l over the 16 key lanes -> full per-q sums
        #pragma unroll
        for (int r = 0; r < 4; ++r) {
            float a = li0[r], b = li1[r];
            a += __shfl_xor(a, 1); a += __shfl_xor(a, 2);
            a += __shfl_xor(a, 4); a += __shfl_xor(a, 8);
            b += __shfl_xor(b, 1); b += __shfl_xor(b, 2);
            b += __shfl_xor(b, 4); b += __shfl_xor(b, 8);
            if (lane16 == 0) {
                lsum[qs * 32 + quad * 4 + r] = a;
                lsum[qs * 32 + 16 + quad * 4 + r] = b;
            }
        }
        __syncthreads();
    } else {
        // ================= CONSUMER (32q x 256ch per wave) =================
        int cw = w - 2, qs2 = cw & 1, chh = cw >> 1;
        v16f acc[8] = {};
        int q = qs2 * 32 + l31;
        int pswz = (q >> 1) & 1;

        for (int kt = 0; kt <= 64; ++kt) {
            if (kt + 1 < 64) {
                u16* kd = KsB + ((kt + 1) & 1) * 8192;
                const u16* ks = Kb + (size_t)(kt + 1) * 8192;
                for (int u = w; u < 16; u += 6)
                    gl2lds(&ks[u * 512 + l * 8], &kd[u * 512 + l * 8]);
            }
            if (kt < 64) {
                u16* vd = VsB + (kt & 1) * 8192;
                const u16* vs = Vb + (size_t)kt * 8192;
                for (int u = w; u < 16; u += 6)
                    gl2lds(&vs[u * 512 + l * 8], &vd[u * 512 + l * 8]);
            }
            if (kt >= 1) {
                int kp = (kt - 1) & 1;
                const u16* Pt  = Pb + kp * 1024;
                const u16* VsT = VsB + kp * 8192;
                v8s pb = *(const v8s*)&Pt[q * 16 + ((s5 ^ pswz) * 8)];
                #pragma unroll
                for (int chb = 0; chb < 8; ++chb) {
                    int ch = chh * 256 + chb * 32 + l31;
                    int p = ch >> 1;
                    v8s vf = *(const v8s*)&VsT[p * 32 +
                                   ((((ch & 1) * 2 + s5) ^ (p & 3)) * 8)];
                    acc[chb] = MFMA32(vf, pb, acc[chb]);
                }
            }
            __syncthreads();
        }
        __syncthreads();   // wait for lsum
        float inv = 1.0f / lsum[q];
        int token = bz * 1024 + qb * 64 + q;
        #pragma unroll
        for (int chb = 0; chb < 8; ++chb) {
            #pragma unroll
            for (int rg = 0; rg < 4; ++rg) {
                int ch0 = chh * 256 + chb * 32 + rg * 8 + s5 * 4;
                u16 o4[4];
                #pragma unroll
                for (int i = 0; i < 4; ++i) o4[i] = f2bf(acc[chb][rg * 4 + i] * inv);
                *(uint2*)&O[(size_t)token * 512 + ch0] = *(const uint2*)o4;
            }
        }
    }
}

// ---------------------------------------------------------------------------
// Proj GEMM + residual, BK=64, counted-vmcnt double-buffer K-loop (round-6):
// out[b][c][token] = x + Wp @ O_b^T + bp
// ---------------------------------------------------------------------------
__global__ __launch_bounds__(256, 2) void gemm_proj(
    const u16* __restrict__ Wp, const u16* __restrict__ O,
    const float* __restrict__ x, const float* __restrict__ bp,
    float* __restrict__ out) {
    int n0 = blockIdx.x * 128, m0 = blockIdx.y * 128, b = blockIdx.z;
    __shared__ alignas(16) u16 As[2 * 8192];
    __shared__ alignas(16) u16 Bs[2 * 8192];
    int t = threadIdx.x, w = t >> 6, l = t & 63;
    int lane16 = l & 15, quad = l >> 4;
    int wm = w & 1, wn = w >> 1;
    v4f acc[4][4] = {};

#define STAGE_PRJ(buf, k0)                                                     \
    {                                                                          \
        _Pragma("unroll")                                                      \
        for (int i_ = 0; i_ < 4; ++i_) {                                       \
            int id_ = i_ * 256 + t, row_ = id_ >> 3, c_ = id_ & 7;             \
            int sc_ = c_ ^ (row_ & 7);                                         \
            gl2lds(&Wp[(size_t)(m0 + row_) * 512 + (k0) + sc_ * 8],            \
                   &As[(buf) * 8192 + row_ * 64 + c_ * 8]);                    \
            gl2lds(&O[(size_t)(b * 1024 + n0 + row_) * 512 + (k0) + sc_ * 8],  \
                   &Bs[(buf) * 8192 + row_ * 64 + c_ * 8]);                    \
        }                                                                      \
    }

    STAGE_PRJ(0, 0);
    STAGE_PRJ(1, 64);
    asm volatile("s_waitcnt vmcnt(8)" ::: "memory");
    __builtin_amdgcn_s_barrier();
    __builtin_amdgcn_sched_barrier(0);

    for (int tt = 0; tt < 8; ++tt) {
        int cb = (tt & 1) * 8192;
        #pragma unroll
        for (int hh = 0; hh < 2; ++hh) {
            v8s af[4], bf[4];
            #pragma unroll
            for (int i = 0; i < 4; ++i) {
                int row = wm * 64 + i * 16 + lane16;
                af[i] = *(const v8s*)&As[cb + row * 64 +
                                         (((hh * 4 + quad) ^ (lane16 & 7)) * 8)];
            }
            #pragma unroll
            for (int j = 0; j < 4; ++j) {
                int row = wn * 64 + j * 16 + lane16;
                bf[j] = *(const v8s*)&Bs[cb + row * 64 +
                                         (((hh * 4 + quad) ^ (lane16 & 7)) * 8)];
            }
            #pragma unroll
            for (int i = 0; i < 4; ++i)
                #pragma unroll
                for (int j = 0; j < 4; ++j)
                    acc[i][j] = MFMA16(af[i], bf[j], acc[i][j]);
        }
        __builtin_amdgcn_s_barrier();
        __builtin_amdgcn_sched_barrier(0);
        if (tt + 2 < 8) {
            STAGE_PRJ(tt & 1, (tt + 2) * 64);
            asm volatile("s_waitcnt vmcnt(8)" ::: "memory");
        } else {
            asm volatile("s_waitcnt vmcnt(0)" ::: "memory");
        }
        __builtin_amdgcn_s_barrier();
        __builtin_amdgcn_sched_barrier(0);
    }
#undef STAGE_PRJ

    #pragma unroll
    for (int i = 0; i < 4; ++i) {
        #pragma unroll
        for (int r = 0; r < 4; ++r) {
            int row = wm * 64 + i * 16 + quad * 4 + r;
            float bia = bp[m0 + row];
            #pragma unroll
            for (int j = 0; j < 4; ++j) {
                int col = wn * 64 + j * 16 + lane16;
                size_t idx = (size_t)(b * 512 + m0 + row) * 1024 + n0 + col;
                out[idx] = acc[i][j][r] + bia + x[idx];
            }
        }
    }
}

// ---------------------------------------------------------------------------
extern "C" void kernel_launch(void* const* d_in, const int* in_sizes, int n_in,
                              void* d_out, int out_size, void* d_ws, size_t ws_size,
                              hipStream_t stream) {
    (void)in_sizes; (void)n_in; (void)out_size; (void)ws_size;
    const float* x   = (const float*)d_in[0];
    const float* gnw = (const float*)d_in[1];
    const float* gnb = (const float*)d_in[2];
    const float* wq  = (const float*)d_in[3];
    const float* bq  = (const float*)d_in[4];
    const float* wk  = (const float*)d_in[5];
    const float* bk  = (const float*)d_in[6];
    const float* wv  = (const float*)d_in[7];
    const float* bv  = (const float*)d_in[8];
    const float* wp  = (const float*)d_in[9];
    const float* bp  = (const float*)d_in[10];
    float* out = (float*)d_out;

    char* ws = (char*)d_ws;
    u16*    Wqkv  = (u16*)(ws + 0);                       // 1.5 MB
    u16*    Wp    = (u16*)(ws + 1572864);                 // 0.5 MB
    float*  bqkv  = (float*)(ws + 2097152);               // 6 KB
    float2* stats = (float2*)(ws + 2105344);              // 8 KB
    u16*    h     = (u16*)(ws + 4194304ULL);              // 32 MB (reused as O)
    u16*    Qb    = (u16*)(ws + 4194304ULL + 33554432ULL);        // 32 MB
    u16*    Kb    = (u16*)(ws + 4194304ULL + 2ULL * 33554432ULL); // 32 MB tiled/swizzled
    u16*    Vb    = (u16*)(ws + 4194304ULL + 3ULL * 33554432ULL); // 32 MB tiled/swizzled

    prep_kernel<<<4096, 256, 0, stream>>>(wq, wk, wv, wp, bq, bk, bv, Wqkv, Wp, bqkv);
    gn_stats<<<dim3(32, 32), 256, 0, stream>>>(x, stats);
    gn_apply<<<dim3(16, 32), 256, 0, stream>>>(x, stats, gnw, gnb, h);
    gemm_qkv<<<dim3(12, 256), 256, 0, stream>>>(h, Wqkv, bqkv, Qb, Kb, Vb);
    flash_attn<<<512, 384, 0, stream>>>(Qb, Kb, Vb, h /* -> O */);
    gemm_proj<<<dim3(8, 4, 32), 256, 0, stream>>>(Wp, h /* O */, x, bp, out);
}

// Round 8
// 336.063 us; speedup vs baseline: 1.1452x; 1.1452x over previous
//
#include <hip/hip_runtime.h>

typedef unsigned short u16;
typedef unsigned int u32;
typedef short v8s __attribute__((ext_vector_type(8)));
typedef float v4f __attribute__((ext_vector_type(4)));
typedef float v16f __attribute__((ext_vector_type(16)));

#define MFMA16(a, b, c) __builtin_amdgcn_mfma_f32_16x16x32_bf16((a), (b), (c), 0, 0, 0)
#define MFMA32(a, b, c) __builtin_amdgcn_mfma_f32_32x32x16_bf16((a), (b), (c), 0, 0, 0)

static __device__ __forceinline__ u16 f2bf(float f) {
    u32 u = __float_as_uint(f);
    u += 0x7fffu + ((u >> 16) & 1u);   // RNE
    return (u16)(u >> 16);
}

// async global->LDS, 16B per lane. LDS dest must be wave-uniform base + lane*16.
static __device__ __forceinline__ void gl2lds(const u16* g, u16* l) {
    __builtin_amdgcn_global_load_lds(
        (const __attribute__((address_space(1))) void*)g,
        (__attribute__((address_space(3))) void*)l, 16, 0, 0);
}

// ---------------------------------------------------------------------------
// GroupNorm pass 1 + fused weight prep.
//  * stats: per (b,g) mean & rsigma over 16 ch x 1024 spatial.
//  * prep (fused, grid-strided): fp32 weights -> bf16 (Wqkv packed
//    [1536][512], Wp [512][512]) + bias pack. 1024 blocks x 256 thr x 4
//    elems = 1,048,576; 4-chunks never straddle the 262144-elem segment
//    boundaries, so each chunk is one float4 read + one uint2 write.
// ---------------------------------------------------------------------------
__global__ __launch_bounds__(256) void gn_stats(
    const float* __restrict__ x, float2* __restrict__ stats,
    const float* __restrict__ wq, const float* __restrict__ wk,
    const float* __restrict__ wv, const float* __restrict__ wp,
    const float* __restrict__ bq, const float* __restrict__ bk,
    const float* __restrict__ bv,
    u16* __restrict__ Wqkv, u16* __restrict__ Wp, float* __restrict__ bqkv) {
    int g = blockIdx.x, b = blockIdx.y;
    int t = threadIdx.x;

    // ---- fused prep ----
    {
        int bid = b * 32 + g;              // 0..1023
        int base = bid * 1024 + t * 4;     // 0..1048572, 4-aligned
        float4 v;
        if (base < 262144)      v = *(const float4*)&wq[base];
        else if (base < 524288) v = *(const float4*)&wk[base - 262144];
        else if (base < 786432) v = *(const float4*)&wv[base - 524288];
        else                    v = *(const float4*)&wp[base - 786432];
        u16 o[4] = { f2bf(v.x), f2bf(v.y), f2bf(v.z), f2bf(v.w) };
        if (base < 786432) *(uint2*)&Wqkv[base] = *(const uint2*)o;
        else               *(uint2*)&Wp[base - 786432] = *(const uint2*)o;
        if (bid == 0 && t < 384) {
            int id0 = t * 4;
            #pragma unroll
            for (int i = 0; i < 4; ++i) {
                int id = id0 + i;
                float bb = (id < 512) ? bq[id]
                         : (id < 1024 ? bk[id - 512] : bv[id - 1024]);
                bqkv[id] = bb;
            }
        }
    }

    // ---- stats ----
    const float4* x4 = (const float4*)x + (size_t)(b * 512 + g * 16) * 256;
    float s = 0.f, s2 = 0.f;
    for (int i = t; i < 4096; i += 256) {
        float4 v = x4[i];
        s  += v.x + v.y + v.z + v.w;
        s2 += v.x * v.x + v.y * v.y + v.z * v.z + v.w * v.w;
    }
    #pragma unroll
    for (int d = 1; d < 64; d <<= 1) { s += __shfl_xor(s, d); s2 += __shfl_xor(s2, d); }
    __shared__ float red1[4], red2[4];
    int w = t >> 6;
    if ((t & 63) == 0) { red1[w] = s; red2[w] = s2; }
    __syncthreads();
    if (t == 0) {
        s = red1[0] + red1[1] + red1[2] + red1[3];
        s2 = red2[0] + red2[1] + red2[2] + red2[3];
        float mu = s * (1.0f / 16384.0f);
        float var = s2 * (1.0f / 16384.0f) - mu * mu;
        stats[b * 32 + g] = make_float2(mu, rsqrtf(var + 1e-5f));
    }
}

// ---------------------------------------------------------------------------
// GroupNorm pass 2 + transpose: x[b,c,s] fp32 -> h[b*1024+s][c] bf16 (token-major)
// ---------------------------------------------------------------------------
__global__ __launch_bounds__(256) void gn_apply(
    const float* __restrict__ x, const float2* __restrict__ stats,
    const float* __restrict__ gnw, const float* __restrict__ gnb,
    u16* __restrict__ h) {
    int st = blockIdx.x, b = blockIdx.y;
    int s0 = st * 64;
    __shared__ float smu[32], srs[32], sw[512], sbv[512];
    __shared__ alignas(16) u16 hs[64][520];
    int t = threadIdx.x;
    if (t < 32) { float2 v = stats[b * 32 + t]; smu[t] = v.x; srs[t] = v.y; }
    sw[t] = gnw[t]; sw[t + 256] = gnw[t + 256];
    sbv[t] = gnb[t]; sbv[t + 256] = gnb[t + 256];
    __syncthreads();
    #pragma unroll 4
    for (int it = 0; it < 32; ++it) {
        int id = it * 256 + t;
        int c = id >> 4, f4 = id & 15;
        float4 v = ((const float4*)x)[(size_t)(b * 512 + c) * 256 + (s0 >> 2) + f4];
        int g = c >> 4;
        float mu = smu[g], r = srs[g], wgt = sw[c], bia = sbv[c];
        hs[f4 * 4 + 0][c] = f2bf((v.x - mu) * r * wgt + bia);
        hs[f4 * 4 + 1][c] = f2bf((v.y - mu) * r * wgt + bia);
        hs[f4 * 4 + 2][c] = f2bf((v.z - mu) * r * wgt + bia);
        hs[f4 * 4 + 3][c] = f2bf((v.w - mu) * r * wgt + bia);
    }
    __syncthreads();
    int lane = t & 63, wrow = t >> 6;
    #pragma unroll 4
    for (int it = 0; it < 16; ++it) {
        int s = it * 4 + wrow;
        float4 vv = *(const float4*)&hs[s][lane * 8];
        *((float4*)h + (size_t)(b * 1024 + s0 + s) * 64 + lane) = vv;
    }
}

// ---------------------------------------------------------------------------
// QKV GEMM, BK=64, double-buffered counted-vmcnt K-loop (round-6, passed).
// Q: token-major, pre-scaled by 512^-0.5.
// K: per-(batch, 32-key tile) image [32 key][512 ch]; 16B blocks (64/row)
//    XOR-swizzled by (key&7).
// V: per-tile image [512 ch][32 key]; 16B blocks (4/row) XOR-swizzled by
//    ((ch>>1)&3). Both images copied verbatim to LDS by flash_attn.
// ---------------------------------------------------------------------------
__global__ __launch_bounds__(256, 2) void gemm_qkv(
    const u16* __restrict__ h, const u16* __restrict__ Wqkv,
    const float* __restrict__ bqkv,
    u16* __restrict__ Qo, u16* __restrict__ Ko, u16* __restrict__ Vo) {
    int n0 = blockIdx.x * 128, m0 = blockIdx.y * 128;
    __shared__ alignas(16) char ldsb[65536];
    u16* As = (u16*)ldsb;             // [2][128][64]  32 KB
    u16* Bs = (u16*)(ldsb + 32768);   // [2][128][64]  32 KB
    u16* Tr = (u16*)ldsb;             // [128][136] epilogue overlay
    int t = threadIdx.x, w = t >> 6, l = t & 63;
    int lane16 = l & 15, quad = l >> 4;
    int wm = w & 1, wn = w >> 1;
    v4f acc[4][4] = {};

#define STAGE_QKV(buf, k0)                                                     \
    {                                                                          \
        _Pragma("unroll")                                                      \
        for (int i_ = 0; i_ < 4; ++i_) {                                       \
            int id_ = i_ * 256 + t, row_ = id_ >> 3, c_ = id_ & 7;             \
            int sc_ = c_ ^ (row_ & 7);                                         \
            gl2lds(&h[(size_t)(m0 + row_) * 512 + (k0) + sc_ * 8],             \
                   &As[(buf) * 8192 + row_ * 64 + c_ * 8]);                    \
            gl2lds(&Wqkv[(size_t)(n0 + row_) * 512 + (k0) + sc_ * 8],          \
                   &Bs[(buf) * 8192 + row_ * 64 + c_ * 8]);                    \
        }                                                                      \
    }

    STAGE_QKV(0, 0);
    STAGE_QKV(1, 64);
    asm volatile("s_waitcnt vmcnt(8)" ::: "memory");
    __builtin_amdgcn_s_barrier();
    __builtin_amdgcn_sched_barrier(0);

    for (int tt = 0; tt < 8; ++tt) {
        int cb = (tt & 1) * 8192;
        #pragma unroll
        for (int hh = 0; hh < 2; ++hh) {
            v8s af[4], bf[4];
            #pragma unroll
            for (int i = 0; i < 4; ++i) {
                int row = wm * 64 + i * 16 + lane16;
                af[i] = *(const v8s*)&As[cb + row * 64 +
                                         (((hh * 4 + quad) ^ (lane16 & 7)) * 8)];
            }
            #pragma unroll
            for (int j = 0; j < 4; ++j) {
                int row = wn * 64 + j * 16 + lane16;
                bf[j] = *(const v8s*)&Bs[cb + row * 64 +
                                         (((hh * 4 + quad) ^ (lane16 & 7)) * 8)];
            }
            #pragma unroll
            for (int i = 0; i < 4; ++i)
                #pragma unroll
                for (int j = 0; j < 4; ++j)
                    acc[i][j] = MFMA16(af[i], bf[j], acc[i][j]);
        }
        __builtin_amdgcn_s_barrier();              // all readers of buf done
        __builtin_amdgcn_sched_barrier(0);
        if (tt + 2 < 8) {
            STAGE_QKV(tt & 1, (tt + 2) * 64);      // refill freed buffer
            asm volatile("s_waitcnt vmcnt(8)" ::: "memory");   // L(t+1) landed
        } else {
            asm volatile("s_waitcnt vmcnt(0)" ::: "memory");   // tail drain
        }
        __builtin_amdgcn_s_barrier();              // everyone's next buf ready
        __builtin_amdgcn_sched_barrier(0);
    }
#undef STAGE_QKV

    float bias[4];
    #pragma unroll
    for (int j = 0; j < 4; ++j) bias[j] = bqkv[n0 + wn * 64 + j * 16 + lane16];

    if (n0 < 1024) {
        // Q or K: stage [token][channel] tile in LDS (Tr overlays As/Bs)
        const float qscale = (n0 < 512) ? 0.04419417382415922f : 1.0f;
        #pragma unroll
        for (int i = 0; i < 4; ++i)
            #pragma unroll
            for (int j = 0; j < 4; ++j)
                #pragma unroll
                for (int r = 0; r < 4; ++r) {
                    int row = wm * 64 + i * 16 + quad * 4 + r;
                    int col = wn * 64 + j * 16 + lane16;
                    Tr[row * 136 + col] = f2bf((acc[i][j][r] + bias[j]) * qscale);
                }
        __syncthreads();
        if (n0 < 512) {
            #pragma unroll
            for (int it = 0; it < 8; ++it) {
                int id = it * 256 + t, row = id >> 4, ch = id & 15;
                *(float4*)&Qo[(size_t)(m0 + row) * 512 + n0 + ch * 8] =
                    *(const float4*)&Tr[row * 136 + ch * 8];
            }
        } else {
            int c0 = n0 - 512, b = m0 >> 10, sb = m0 & 1023;
            #pragma unroll
            for (int it = 0; it < 8; ++it) {
                int id = it * 256 + t, row = id >> 4, ch = id & 15;
                int s = sb + row, kt = s >> 5, key = s & 31;
                int kb = ((c0 + ch * 8) >> 3) ^ (key & 7);   // XOR swizzle (64 blocks/row)
                *(float4*)&Ko[((size_t)(b * 32 + kt)) * 16384 + key * 512 + kb * 8] =
                    *(const float4*)&Tr[row * 136 + ch * 8];
            }
        }
    } else {
        // V: stage TRANSPOSED [channel][token] in LDS
        #pragma unroll
        for (int i = 0; i < 4; ++i)
            #pragma unroll
            for (int j = 0; j < 4; ++j)
                #pragma unroll
                for (int r = 0; r < 4; ++r) {
                    int row = wm * 64 + i * 16 + quad * 4 + r;
                    int col = wn * 64 + j * 16 + lane16;
                    Tr[col * 136 + row] = f2bf(acc[i][j][r] + bias[j]);
                }
        __syncthreads();
        int c0 = n0 - 1024, b = m0 >> 10, sb = m0 & 1023;
        #pragma unroll
        for (int it = 0; it < 8; ++it) {
            int id = it * 256 + t, c = id >> 4, ch8 = id & 15;
            int key0 = sb + ch8 * 8;                  // 8 consecutive keys
            int kt = key0 >> 5;
            int kblk = (key0 >> 3) & 3;               // block within 4-block row
            int ch = c0 + c;
            int swz = (ch >> 1) & 3;
            *(float4*)&Vo[((size_t)(b * 32 + kt)) * 16384 + (size_t)ch * 32 +
                          ((kblk ^ swz) * 8)] =
                *(const float4*)&Tr[c * 136 + ch8 * 8];
        }
    }
}

// ---------------------------------------------------------------------------
// Flash attention v3 (the proven 102.6-104.4 µs kernel, unchanged):
// producer/consumer wave specialization.
// Block = 64 queries, 512 thr / 8 waves, full 1024 keys in 32-key tiles.
//  Waves 0-3 (producers, (qs,kh)): QK for 32q x 16 keys via 16x16x32, Q held
//    as TWO A-frag sets (128 VGPR) -> each K B-read feeds 2 MFMAs. exp() ->
//    P image (double-buffered) + per-row l partials.
//  Waves 4-7 (consumers, (qs2,chh)): PV via 32x32x16: O^T[256ch x 32q],
//    A=V^T from LDS, B=P^T read once per key-16 chunk and reused across 8
//    ch-blocks. Consumers lag producers by 1 tile.
// One barrier per tile; K/V/P double-buffered; stages issued right after the
// barrier fly under the whole compute phase. All LDS patterns bank-uniform.
// ---------------------------------------------------------------------------
__global__ __launch_bounds__(512, 2) void flash_attn(
    const u16* __restrict__ Q, const u16* __restrict__ Kt,
    const u16* __restrict__ Vt, u16* __restrict__ O) {
    int idx = blockIdx.x;
    int xcd = idx & 7, j = idx >> 3;          // XCD-aware: 4 batches per XCD
    int bz = xcd * 4 + (j >> 4);
    int qb = j & 15;                          // 64-query block

    __shared__ alignas(16) char lds[139776];
    u16*   KsB  = (u16*)lds;                  // [2][32][512]  64 KB
    u16*   VsB  = (u16*)(lds + 65536);        // [2][512][32]  64 KB
    u16*   Pb   = (u16*)(lds + 131072);       // [2][64][32]    8 KB
    float* lsum = (float*)(lds + 139264);     // [2][64]      0.5 KB

    int t = threadIdx.x, w = t >> 6, l = t & 63;
    int lane16 = l & 15, quad = l >> 4;
    int s5 = l >> 5, l31 = l & 31;

    const u16* Kb = Kt + (size_t)bz * 32 * 16384;
    const u16* Vb = Vt + (size_t)bz * 32 * 16384;

    // prologue: stage K tile 0 (each wave copies 4 KB of the 32 KB tile)
    #pragma unroll
    for (int c = 0; c < 4; ++c) {
        int ch = w * 4 + c;
        gl2lds(&Kb[ch * 512 + l * 8], &KsB[ch * 512 + l * 8]);
    }
    __syncthreads();

    if (w < 4) {
        // ================= PRODUCER =================
        int qs = w & 1, kh = w >> 1;
        int qrow = bz * 1024 + qb * 64 + qs * 32 + lane16;
        v8s qf0[16], qf1[16];
        #pragma unroll
        for (int kk = 0; kk < 16; ++kk) {
            qf0[kk] = *(const v8s*)&Q[(size_t)qrow * 512 + kk * 32 + quad * 8];
            qf1[kk] = *(const v8s*)&Q[(size_t)(qrow + 16) * 512 + kk * 32 + quad * 8];
        }
        v4f li0 = {}, li1 = {};
        int key = kh * 16 + lane16;
        int krowoff = key * 512;
        int kswz = lane16 & 7;

        for (int kt = 0; kt <= 32; ++kt) {
            if (kt + 1 < 32) {
                u16* kd = KsB + ((kt + 1) & 1) * 16384;
                const u16* ks = Kb + (size_t)(kt + 1) * 16384;
                #pragma unroll
                for (int c = 0; c < 4; ++c) {
                    int ch = w * 4 + c;
                    gl2lds(&ks[ch * 512 + l * 8], &kd[ch * 512 + l * 8]);
                }
            }
            if (kt < 32) {
                u16* vd = VsB + (kt & 1) * 16384;
                const u16* vs = Vb + (size_t)kt * 16384;
                #pragma unroll
                for (int c = 0; c < 4; ++c) {
                    int ch = w * 4 + c;
                    gl2lds(&vs[ch * 512 + l * 8], &vd[ch * 512 + l * 8]);
                }
                const u16* KsT = KsB + (kt & 1) * 16384;
                u16* Pt = Pb + (kt & 1) * 2048;
                v4f sA = {}, sB = {};
                #pragma unroll
                for (int kk = 0; kk < 16; ++kk) {
                    v8s b = *(const v8s*)&KsT[krowoff + (((kk * 4 + quad) ^ kswz) * 8)];
                    sA = MFMA16(qf0[kk], b, sA);
                    sB = MFMA16(qf1[kk], b, sB);
                }
                #pragma unroll
                for (int r = 0; r < 4; ++r) {
                    float p0 = __expf(sA[r]), p1 = __expf(sB[r]);
                    li0[r] += p0; li1[r] += p1;
                    int q0 = qs * 32 + quad * 4 + r, q1 = q0 + 16;
                    Pt[q0 * 32 + (((key >> 3) ^ ((q0 >> 1) & 3)) * 8) + (key & 7)] = f2bf(p0);
                    Pt[q1 * 32 + (((key >> 3) ^ ((q1 >> 1) & 3)) * 8) + (key & 7)] = f2bf(p1);
                }
            }
            __syncthreads();
        }
        // reduce l over the 16 keys of this wave, publish per-kh partials
        #pragma unroll
        for (int r = 0; r < 4; ++r) {
            float a = li0[r], b = li1[r];
            a += __shfl_xor(a, 1); a += __shfl_xor(a, 2);
            a += __shfl_xor(a, 4); a += __shfl_xor(a, 8);
            b += __shfl_xor(b, 1); b += __shfl_xor(b, 2);
            b += __shfl_xor(b, 4); b += __shfl_xor(b, 8);
            if (lane16 == 0) {
                lsum[kh * 64 + qs * 32 + quad * 4 + r] = a;
                lsum[kh * 64 + qs * 32 + 16 + quad * 4 + r] = b;
            }
        }
        __syncthreads();
    } else {
        // ================= CONSUMER =================
        int cw = w - 4, qs2 = cw & 1, chh = cw >> 1;
        v16f acc[8] = {};
        int q = qs2 * 32 + l31;
        int pswz = (q >> 1) & 3;

        for (int kt = 0; kt <= 32; ++kt) {
            if (kt + 1 < 32) {
                u16* kd = KsB + ((kt + 1) & 1) * 16384;
                const u16* ks = Kb + (size_t)(kt + 1) * 16384;
                #pragma unroll
                for (int c = 0; c < 4; ++c) {
                    int ch = w * 4 + c;
                    gl2lds(&ks[ch * 512 + l * 8], &kd[ch * 512 + l * 8]);
                }
            }
            if (kt < 32) {
                u16* vd = VsB + (kt & 1) * 16384;
                const u16* vs = Vb + (size_t)kt * 16384;
                #pragma unroll
                for (int c = 0; c < 4; ++c) {
                    int ch = w * 4 + c;
                    gl2lds(&vs[ch * 512 + l * 8], &vd[ch * 512 + l * 8]);
                }
            }
            if (kt >= 1) {
                int kp = (kt - 1) & 1;
                const u16* Pt  = Pb + kp * 2048;
                const u16* VsT = VsB + kp * 16384;
                #pragma unroll
                for (int kc = 0; kc < 2; ++kc) {
                    v8s pb = *(const v8s*)&Pt[q * 32 + (((kc * 2 + s5) ^ pswz) * 8)];
                    #pragma unroll
                    for (int chb = 0; chb < 8; ++chb) {
                        int ch = chh * 256 + chb * 32 + l31;
                        v8s vf = *(const v8s*)&VsT[ch * 32 +
                                                   (((kc * 2 + s5) ^ ((ch >> 1) & 3)) * 8)];
                        acc[chb] = MFMA32(vf, pb, acc[chb]);
                    }
                }
            }
            __syncthreads();
        }
        __syncthreads();   // wait for lsum
        float inv = 1.0f / (lsum[q] + lsum[64 + q]);
        int token = bz * 1024 + qb * 64 + q;
        #pragma unroll
        for (int chb = 0; chb < 8; ++chb) {
            #pragma unroll
            for (int rg = 0; rg < 4; ++rg) {
                int ch0 = chh * 256 + chb * 32 + rg * 8 + s5 * 4;
                u16 o4[4];
                #pragma unroll
                for (int i = 0; i < 4; ++i) o4[i] = f2bf(acc[chb][rg * 4 + i] * inv);
                *(uint2*)&O[(size_t)token * 512 + ch0] = *(const uint2*)o4;
            }
        }
    }
}

// ---------------------------------------------------------------------------
// Proj GEMM + residual, BK=64, counted-vmcnt double-buffer K-loop (round-6):
// out[b][c][token] = x + Wp @ O_b^T + bp
// ---------------------------------------------------------------------------
__global__ __launch_bounds__(256, 2) void gemm_proj(
    const u16* __restrict__ Wp, const u16* __restrict__ O,
    const float* __restrict__ x, const float* __restrict__ bp,
    float* __restrict__ out) {
    int n0 = blockIdx.x * 128, m0 = blockIdx.y * 128, b = blockIdx.z;
    __shared__ alignas(16) u16 As[2 * 8192];
    __shared__ alignas(16) u16 Bs[2 * 8192];
    int t = threadIdx.x, w = t >> 6, l = t & 63;
    int lane16 = l & 15, quad = l >> 4;
    int wm = w & 1, wn = w >> 1;
    v4f acc[4][4] = {};

#define STAGE_PRJ(buf, k0)                                                     \
    {                                                                          \
        _Pragma("unroll")                                                      \
        for (int i_ = 0; i_ < 4; ++i_) {                                       \
            int id_ = i_ * 256 + t, row_ = id_ >> 3, c_ = id_ & 7;             \
            int sc_ = c_ ^ (row_ & 7);                                         \
            gl2lds(&Wp[(size_t)(m0 + row_) * 512 + (k0) + sc_ * 8],            \
                   &As[(buf) * 8192 + row_ * 64 + c_ * 8]);                    \
            gl2lds(&O[(size_t)(b * 1024 + n0 + row_) * 512 + (k0) + sc_ * 8],  \
                   &Bs[(buf) * 8192 + row_ * 64 + c_ * 8]);                    \
        }                                                                      \
    }

    STAGE_PRJ(0, 0);
    STAGE_PRJ(1, 64);
    asm volatile("s_waitcnt vmcnt(8)" ::: "memory");
    __builtin_amdgcn_s_barrier();
    __builtin_amdgcn_sched_barrier(0);

    for (int tt = 0; tt < 8; ++tt) {
        int cb = (tt & 1) * 8192;
        #pragma unroll
        for (int hh = 0; hh < 2; ++hh) {
            v8s af[4], bf[4];
            #pragma unroll
            for (int i = 0; i < 4; ++i) {
                int row = wm * 64 + i * 16 + lane16;
                af[i] = *(const v8s*)&As[cb + row * 64 +
                                         (((hh * 4 + quad) ^ (lane16 & 7)) * 8)];
            }
            #pragma unroll
            for (int j = 0; j < 4; ++j) {
                int row = wn * 64 + j * 16 + lane16;
                bf[j] = *(const v8s*)&Bs[cb + row * 64 +
                                         (((hh * 4 + quad) ^ (lane16 & 7)) * 8)];
            }
            #pragma unroll
            for (int i = 0; i < 4; ++i)
                #pragma unroll
                for (int j = 0; j < 4; ++j)
                    acc[i][j] = MFMA16(af[i], bf[j], acc[i][j]);
        }
        __builtin_amdgcn_s_barrier();
        __builtin_amdgcn_sched_barrier(0);
        if (tt + 2 < 8) {
            STAGE_PRJ(tt & 1, (tt + 2) * 64);
            asm volatile("s_waitcnt vmcnt(8)" ::: "memory");
        } else {
            asm volatile("s_waitcnt vmcnt(0)" ::: "memory");
        }
        __builtin_amdgcn_s_barrier();
        __builtin_amdgcn_sched_barrier(0);
    }
#undef STAGE_PRJ

    #pragma unroll
    for (int i = 0; i < 4; ++i) {
        #pragma unroll
        for (int r = 0; r < 4; ++r) {
            int row = wm * 64 + i * 16 + quad * 4 + r;
            float bia = bp[m0 + row];
            #pragma unroll
            for (int j = 0; j < 4; ++j) {
                int col = wn * 64 + j * 16 + lane16;
                size_t idx = (size_t)(b * 512 + m0 + row) * 1024 + n0 + col;
                out[idx] = acc[i][j][r] + bia + x[idx];
            }
        }
    }
}

// ---------------------------------------------------------------------------
extern "C" void kernel_launch(void* const* d_in, const int* in_sizes, int n_in,
                              void* d_out, int out_size, void* d_ws, size_t ws_size,
                              hipStream_t stream) {
    (void)in_sizes; (void)n_in; (void)out_size; (void)ws_size;
    const float* x   = (const float*)d_in[0];
    const float* gnw = (const float*)d_in[1];
    const float* gnb = (const float*)d_in[2];
    const float* wq  = (const float*)d_in[3];
    const float* bq  = (const float*)d_in[4];
    const float* wk  = (const float*)d_in[5];
    const float* bk  = (const float*)d_in[6];
    const float* wv  = (const float*)d_in[7];
    const float* bv  = (const float*)d_in[8];
    const float* wp  = (const float*)d_in[9];
    const float* bp  = (const float*)d_in[10];
    float* out = (float*)d_out;

    char* ws = (char*)d_ws;
    u16*    Wqkv  = (u16*)(ws + 0);                       // 1.5 MB
    u16*    Wp    = (u16*)(ws + 1572864);                 // 0.5 MB
    float*  bqkv  = (float*)(ws + 2097152);               // 6 KB
    float2* stats = (float2*)(ws + 2105344);              // 8 KB
    u16*    h     = (u16*)(ws + 4194304ULL);              // 32 MB (reused as O)
    u16*    Qb    = (u16*)(ws + 4194304ULL + 33554432ULL);        // 32 MB
    u16*    Kb    = (u16*)(ws + 4194304ULL + 2ULL * 33554432ULL); // 32 MB tiled/swizzled
    u16*    Vb    = (u16*)(ws + 4194304ULL + 3ULL * 33554432ULL); // 32 MB tiled/swizzled

    gn_stats<<<dim3(32, 32), 256, 0, stream>>>(x, stats, wq, wk, wv, wp,
                                               bq, bk, bv, Wqkv, Wp, bqkv);
    gn_apply<<<dim3(16, 32), 256, 0, stream>>>(x, stats, gnw, gnb, h);
    gemm_qkv<<<dim3(12, 256), 256, 0, stream>>>(h, Wqkv, bqkv, Qb, Kb, Vb);
    flash_attn<<<512, 512, 0, stream>>>(Qb, Kb, Vb, h /* -> O */);
    gemm_proj<<<dim3(8, 4, 32), 256, 0, stream>>>(Wp, h /* O */, x, bp, out);
}

// Round 9
// 323.330 us; speedup vs baseline: 1.1903x; 1.0394x over previous
//
#include <hip/hip_runtime.h>

typedef unsigned short u16;
typedef unsigned int u32;
typedef short v8s __attribute__((ext_vector_type(8)));
typedef float v4f __attribute__((ext_vector_type(4)));
typedef float v16f __attribute__((ext_vector_type(16)));

#define MFMA16(a, b, c) __builtin_amdgcn_mfma_f32_16x16x32_bf16((a), (b), (c), 0, 0, 0)
#define MFMA32(a, b, c) __builtin_amdgcn_mfma_f32_32x32x16_bf16((a), (b), (c), 0, 0, 0)

static __device__ __forceinline__ u16 f2bf(float f) {
    u32 u = __float_as_uint(f);
    u += 0x7fffu + ((u >> 16) & 1u);   // RNE
    return (u16)(u >> 16);
}

// async global->LDS, 16B per lane. LDS dest must be wave-uniform base + lane*16.
static __device__ __forceinline__ void gl2lds(const u16* g, u16* l) {
    __builtin_amdgcn_global_load_lds(
        (const __attribute__((address_space(1))) void*)g,
        (__attribute__((address_space(3))) void*)l, 16, 0, 0);
}

// ---------------------------------------------------------------------------
// GroupNorm pass 1 + fused weight prep (round-8, banked).
// ---------------------------------------------------------------------------
__global__ __launch_bounds__(256) void gn_stats(
    const float* __restrict__ x, float2* __restrict__ stats,
    const float* __restrict__ wq, const float* __restrict__ wk,
    const float* __restrict__ wv, const float* __restrict__ wp,
    const float* __restrict__ bq, const float* __restrict__ bk,
    const float* __restrict__ bv,
    u16* __restrict__ Wqkv, u16* __restrict__ Wp, float* __restrict__ bqkv) {
    int g = blockIdx.x, b = blockIdx.y;
    int t = threadIdx.x;

    // ---- fused prep ----
    {
        int bid = b * 32 + g;              // 0..1023
        int base = bid * 1024 + t * 4;     // 0..1048572, 4-aligned
        float4 v;
        if (base < 262144)      v = *(const float4*)&wq[base];
        else if (base < 524288) v = *(const float4*)&wk[base - 262144];
        else if (base < 786432) v = *(const float4*)&wv[base - 524288];
        else                    v = *(const float4*)&wp[base - 786432];
        u16 o[4] = { f2bf(v.x), f2bf(v.y), f2bf(v.z), f2bf(v.w) };
        if (base < 786432) *(uint2*)&Wqkv[base] = *(const uint2*)o;
        else               *(uint2*)&Wp[base - 786432] = *(const uint2*)o;
        if (bid == 0 && t < 384) {
            int id0 = t * 4;
            #pragma unroll
            for (int i = 0; i < 4; ++i) {
                int id = id0 + i;
                float bb = (id < 512) ? bq[id]
                         : (id < 1024 ? bk[id - 512] : bv[id - 1024]);
                bqkv[id] = bb;
            }
        }
    }

    // ---- stats ----
    const float4* x4 = (const float4*)x + (size_t)(b * 512 + g * 16) * 256;
    float s = 0.f, s2 = 0.f;
    for (int i = t; i < 4096; i += 256) {
        float4 v = x4[i];
        s  += v.x + v.y + v.z + v.w;
        s2 += v.x * v.x + v.y * v.y + v.z * v.z + v.w * v.w;
    }
    #pragma unroll
    for (int d = 1; d < 64; d <<= 1) { s += __shfl_xor(s, d); s2 += __shfl_xor(s2, d); }
    __shared__ float red1[4], red2[4];
    int w = t >> 6;
    if ((t & 63) == 0) { red1[w] = s; red2[w] = s2; }
    __syncthreads();
    if (t == 0) {
        s = red1[0] + red1[1] + red1[2] + red1[3];
        s2 = red2[0] + red2[1] + red2[2] + red2[3];
        float mu = s * (1.0f / 16384.0f);
        float var = s2 * (1.0f / 16384.0f) - mu * mu;
        stats[b * 32 + g] = make_float2(mu, rsqrtf(var + 1e-5f));
    }
}

// ---------------------------------------------------------------------------
// GroupNorm pass 2 + transpose: x[b,c,s] fp32 -> h[b*1024+s][c] bf16 (token-major)
// ---------------------------------------------------------------------------
__global__ __launch_bounds__(256) void gn_apply(
    const float* __restrict__ x, const float2* __restrict__ stats,
    const float* __restrict__ gnw, const float* __restrict__ gnb,
    u16* __restrict__ h) {
    int st = blockIdx.x, b = blockIdx.y;
    int s0 = st * 64;
    __shared__ float smu[32], srs[32], sw[512], sbv[512];
    __shared__ alignas(16) u16 hs[64][520];
    int t = threadIdx.x;
    if (t < 32) { float2 v = stats[b * 32 + t]; smu[t] = v.x; srs[t] = v.y; }
    sw[t] = gnw[t]; sw[t + 256] = gnw[t + 256];
    sbv[t] = gnb[t]; sbv[t + 256] = gnb[t + 256];
    __syncthreads();
    #pragma unroll 4
    for (int it = 0; it < 32; ++it) {
        int id = it * 256 + t;
        int c = id >> 4, f4 = id & 15;
        float4 v = ((const float4*)x)[(size_t)(b * 512 + c) * 256 + (s0 >> 2) + f4];
        int g = c >> 4;
        float mu = smu[g], r = srs[g], wgt = sw[c], bia = sbv[c];
        hs[f4 * 4 + 0][c] = f2bf((v.x - mu) * r * wgt + bia);
        hs[f4 * 4 + 1][c] = f2bf((v.y - mu) * r * wgt + bia);
        hs[f4 * 4 + 2][c] = f2bf((v.z - mu) * r * wgt + bia);
        hs[f4 * 4 + 3][c] = f2bf((v.w - mu) * r * wgt + bia);
    }
    __syncthreads();
    int lane = t & 63, wrow = t >> 6;
    #pragma unroll 4
    for (int it = 0; it < 16; ++it) {
        int s = it * 4 + wrow;
        float4 vv = *(const float4*)&hs[s][lane * 8];
        *((float4*)h + (size_t)(b * 1024 + s0 + s) * 64 + lane) = vv;
    }
}

// ---------------------------------------------------------------------------
// QKV GEMM, BK=64, counted-vmcnt double-buffer (round-6) + T1 XCD-aware
// block swizzle: virtual id v = (lin&7)*384 + lin>>3 clusters 32 consecutive
// m0-panels x all 12 n0 per XCD -> per-XCD h working set = 4 MB = one L2;
// the 12 same-m0 blocks hit the h panel in L2 instead of re-fetching via L3.
// ---------------------------------------------------------------------------
__global__ __launch_bounds__(256, 2) void gemm_qkv(
    const u16* __restrict__ h, const u16* __restrict__ Wqkv,
    const float* __restrict__ bqkv,
    u16* __restrict__ Qo, u16* __restrict__ Ko, u16* __restrict__ Vo) {
    int lin = blockIdx.x + 12 * blockIdx.y;        // hardware linear id
    int v = (lin & 7) * 384 + (lin >> 3);          // bijective (3072 % 8 == 0)
    int n0 = (v % 12) * 128, m0 = (v / 12) * 128;
    __shared__ alignas(16) char ldsb[65536];
    u16* As = (u16*)ldsb;             // [2][128][64]  32 KB
    u16* Bs = (u16*)(ldsb + 32768);   // [2][128][64]  32 KB
    u16* Tr = (u16*)ldsb;             // [128][136] epilogue overlay
    int t = threadIdx.x, w = t >> 6, l = t & 63;
    int lane16 = l & 15, quad = l >> 4;
    int wm = w & 1, wn = w >> 1;
    v4f acc[4][4] = {};

#define STAGE_QKV(buf, k0)                                                     \
    {                                                                          \
        _Pragma("unroll")                                                      \
        for (int i_ = 0; i_ < 4; ++i_) {                                       \
            int id_ = i_ * 256 + t, row_ = id_ >> 3, c_ = id_ & 7;             \
            int sc_ = c_ ^ (row_ & 7);                                         \
            gl2lds(&h[(size_t)(m0 + row_) * 512 + (k0) + sc_ * 8],             \
                   &As[(buf) * 8192 + row_ * 64 + c_ * 8]);                    \
            gl2lds(&Wqkv[(size_t)(n0 + row_) * 512 + (k0) + sc_ * 8],          \
                   &Bs[(buf) * 8192 + row_ * 64 + c_ * 8]);                    \
        }                                                                      \
    }

    STAGE_QKV(0, 0);
    STAGE_QKV(1, 64);
    asm volatile("s_waitcnt vmcnt(8)" ::: "memory");
    __builtin_amdgcn_s_barrier();
    __builtin_amdgcn_sched_barrier(0);

    for (int tt = 0; tt < 8; ++tt) {
        int cb = (tt & 1) * 8192;
        #pragma unroll
        for (int hh = 0; hh < 2; ++hh) {
            v8s af[4], bf[4];
            #pragma unroll
            for (int i = 0; i < 4; ++i) {
                int row = wm * 64 + i * 16 + lane16;
                af[i] = *(const v8s*)&As[cb + row * 64 +
                                         (((hh * 4 + quad) ^ (lane16 & 7)) * 8)];
            }
            #pragma unroll
            for (int j = 0; j < 4; ++j) {
                int row = wn * 64 + j * 16 + lane16;
                bf[j] = *(const v8s*)&Bs[cb + row * 64 +
                                         (((hh * 4 + quad) ^ (lane16 & 7)) * 8)];
            }
            #pragma unroll
            for (int i = 0; i < 4; ++i)
                #pragma unroll
                for (int j = 0; j < 4; ++j)
                    acc[i][j] = MFMA16(af[i], bf[j], acc[i][j]);
        }
        __builtin_amdgcn_s_barrier();              // all readers of buf done
        __builtin_amdgcn_sched_barrier(0);
        if (tt + 2 < 8) {
            STAGE_QKV(tt & 1, (tt + 2) * 64);      // refill freed buffer
            asm volatile("s_waitcnt vmcnt(8)" ::: "memory");   // L(t+1) landed
        } else {
            asm volatile("s_waitcnt vmcnt(0)" ::: "memory");   // tail drain
        }
        __builtin_amdgcn_s_barrier();              // everyone's next buf ready
        __builtin_amdgcn_sched_barrier(0);
    }
#undef STAGE_QKV

    float bias[4];
    #pragma unroll
    for (int j = 0; j < 4; ++j) bias[j] = bqkv[n0 + wn * 64 + j * 16 + lane16];

    if (n0 < 1024) {
        // Q or K: stage [token][channel] tile in LDS (Tr overlays As/Bs)
        const float qscale = (n0 < 512) ? 0.04419417382415922f : 1.0f;
        #pragma unroll
        for (int i = 0; i < 4; ++i)
            #pragma unroll
            for (int j = 0; j < 4; ++j)
                #pragma unroll
                for (int r = 0; r < 4; ++r) {
                    int row = wm * 64 + i * 16 + quad * 4 + r;
                    int col = wn * 64 + j * 16 + lane16;
                    Tr[row * 136 + col] = f2bf((acc[i][j][r] + bias[j]) * qscale);
                }
        __syncthreads();
        if (n0 < 512) {
            #pragma unroll
            for (int it = 0; it < 8; ++it) {
                int id = it * 256 + t, row = id >> 4, ch = id & 15;
                *(float4*)&Qo[(size_t)(m0 + row) * 512 + n0 + ch * 8] =
                    *(const float4*)&Tr[row * 136 + ch * 8];
            }
        } else {
            int c0 = n0 - 512, b = m0 >> 10, sb = m0 & 1023;
            #pragma unroll
            for (int it = 0; it < 8; ++it) {
                int id = it * 256 + t, row = id >> 4, ch = id & 15;
                int s = sb + row, kt = s >> 5, key = s & 31;
                int kb = ((c0 + ch * 8) >> 3) ^ (key & 7);   // XOR swizzle (64 blocks/row)
                *(float4*)&Ko[((size_t)(b * 32 + kt)) * 16384 + key * 512 + kb * 8] =
                    *(const float4*)&Tr[row * 136 + ch * 8];
            }
        }
    } else {
        // V: stage TRANSPOSED [channel][token] in LDS
        #pragma unroll
        for (int i = 0; i < 4; ++i)
            #pragma unroll
            for (int j = 0; j < 4; ++j)
                #pragma unroll
                for (int r = 0; r < 4; ++r) {
                    int row = wm * 64 + i * 16 + quad * 4 + r;
                    int col = wn * 64 + j * 16 + lane16;
                    Tr[col * 136 + row] = f2bf(acc[i][j][r] + bias[j]);
                }
        __syncthreads();
        int c0 = n0 - 1024, b = m0 >> 10, sb = m0 & 1023;
        #pragma unroll
        for (int it = 0; it < 8; ++it) {
            int id = it * 256 + t, c = id >> 4, ch8 = id & 15;
            int key0 = sb + ch8 * 8;                  // 8 consecutive keys
            int kt = key0 >> 5;
            int kblk = (key0 >> 3) & 3;               // block within 4-block row
            int ch = c0 + c;
            int swz = (ch >> 1) & 3;
            *(float4*)&Vo[((size_t)(b * 32 + kt)) * 16384 + (size_t)ch * 32 +
                          ((kblk ^ swz) * 8)] =
                *(const float4*)&Tr[c * 136 + ch8 * 8];
        }
    }
}

// ---------------------------------------------------------------------------
// Flash attention v3 (the proven 102.6-106.3 µs kernel, unchanged).
// ---------------------------------------------------------------------------
__global__ __launch_bounds__(512, 2) void flash_attn(
    const u16* __restrict__ Q, const u16* __restrict__ Kt,
    const u16* __restrict__ Vt, u16* __restrict__ O) {
    int idx = blockIdx.x;
    int xcd = idx & 7, j = idx >> 3;          // XCD-aware: 4 batches per XCD
    int bz = xcd * 4 + (j >> 4);
    int qb = j & 15;                          // 64-query block

    __shared__ alignas(16) char lds[139776];
    u16*   KsB  = (u16*)lds;                  // [2][32][512]  64 KB
    u16*   VsB  = (u16*)(lds + 65536);        // [2][512][32]  64 KB
    u16*   Pb   = (u16*)(lds + 131072);       // [2][64][32]    8 KB
    float* lsum = (float*)(lds + 139264);     // [2][64]      0.5 KB

    int t = threadIdx.x, w = t >> 6, l = t & 63;
    int lane16 = l & 15, quad = l >> 4;
    int s5 = l >> 5, l31 = l & 31;

    const u16* Kb = Kt + (size_t)bz * 32 * 16384;
    const u16* Vb = Vt + (size_t)bz * 32 * 16384;

    // prologue: stage K tile 0 (each wave copies 4 KB of the 32 KB tile)
    #pragma unroll
    for (int c = 0; c < 4; ++c) {
        int ch = w * 4 + c;
        gl2lds(&Kb[ch * 512 + l * 8], &KsB[ch * 512 + l * 8]);
    }
    __syncthreads();

    if (w < 4) {
        // ================= PRODUCER =================
        int qs = w & 1, kh = w >> 1;
        int qrow = bz * 1024 + qb * 64 + qs * 32 + lane16;
        v8s qf0[16], qf1[16];
        #pragma unroll
        for (int kk = 0; kk < 16; ++kk) {
            qf0[kk] = *(const v8s*)&Q[(size_t)qrow * 512 + kk * 32 + quad * 8];
            qf1[kk] = *(const v8s*)&Q[(size_t)(qrow + 16) * 512 + kk * 32 + quad * 8];
        }
        v4f li0 = {}, li1 = {};
        int key = kh * 16 + lane16;
        int krowoff = key * 512;
        int kswz = lane16 & 7;

        for (int kt = 0; kt <= 32; ++kt) {
            if (kt + 1 < 32) {
                u16* kd = KsB + ((kt + 1) & 1) * 16384;
                const u16* ks = Kb + (size_t)(kt + 1) * 16384;
                #pragma unroll
                for (int c = 0; c < 4; ++c) {
                    int ch = w * 4 + c;
                    gl2lds(&ks[ch * 512 + l * 8], &kd[ch * 512 + l * 8]);
                }
            }
            if (kt < 32) {
                u16* vd = VsB + (kt & 1) * 16384;
                const u16* vs = Vb + (size_t)kt * 16384;
                #pragma unroll
                for (int c = 0; c < 4; ++c) {
                    int ch = w * 4 + c;
                    gl2lds(&vs[ch * 512 + l * 8], &vd[ch * 512 + l * 8]);
                }
                const u16* KsT = KsB + (kt & 1) * 16384;
                u16* Pt = Pb + (kt & 1) * 2048;
                v4f sA = {}, sB = {};
                #pragma unroll
                for (int kk = 0; kk < 16; ++kk) {
                    v8s b = *(const v8s*)&KsT[krowoff + (((kk * 4 + quad) ^ kswz) * 8)];
                    sA = MFMA16(qf0[kk], b, sA);
                    sB = MFMA16(qf1[kk], b, sB);
                }
                #pragma unroll
                for (int r = 0; r < 4; ++r) {
                    float p0 = __expf(sA[r]), p1 = __expf(sB[r]);
                    li0[r] += p0; li1[r] += p1;
                    int q0 = qs * 32 + quad * 4 + r, q1 = q0 + 16;
                    Pt[q0 * 32 + (((key >> 3) ^ ((q0 >> 1) & 3)) * 8) + (key & 7)] = f2bf(p0);
                    Pt[q1 * 32 + (((key >> 3) ^ ((q1 >> 1) & 3)) * 8) + (key & 7)] = f2bf(p1);
                }
            }
            __syncthreads();
        }
        // reduce l over the 16 keys of this wave, publish per-kh partials
        #pragma unroll
        for (int r = 0; r < 4; ++r) {
            float a = li0[r], b = li1[r];
            a += __shfl_xor(a, 1); a += __shfl_xor(a, 2);
            a += __shfl_xor(a, 4); a += __shfl_xor(a, 8);
            b += __shfl_xor(b, 1); b += __shfl_xor(b, 2);
            b += __shfl_xor(b, 4); b += __shfl_xor(b, 8);
            if (lane16 == 0) {
                lsum[kh * 64 + qs * 32 + quad * 4 + r] = a;
                lsum[kh * 64 + qs * 32 + 16 + quad * 4 + r] = b;
            }
        }
        __syncthreads();
    } else {
        // ================= CONSUMER =================
        int cw = w - 4, qs2 = cw & 1, chh = cw >> 1;
        v16f acc[8] = {};
        int q = qs2 * 32 + l31;
        int pswz = (q >> 1) & 3;

        for (int kt = 0; kt <= 32; ++kt) {
            if (kt + 1 < 32) {
                u16* kd = KsB + ((kt + 1) & 1) * 16384;
                const u16* ks = Kb + (size_t)(kt + 1) * 16384;
                #pragma unroll
                for (int c = 0; c < 4; ++c) {
                    int ch = w * 4 + c;
                    gl2lds(&ks[ch * 512 + l * 8], &kd[ch * 512 + l * 8]);
                }
            }
            if (kt < 32) {
                u16* vd = VsB + (kt & 1) * 16384;
                const u16* vs = Vb + (size_t)kt * 16384;
                #pragma unroll
                for (int c = 0; c < 4; ++c) {
                    int ch = w * 4 + c;
                    gl2lds(&vs[ch * 512 + l * 8], &vd[ch * 512 + l * 8]);
                }
            }
            if (kt >= 1) {
                int kp = (kt - 1) & 1;
                const u16* Pt  = Pb + kp * 2048;
                const u16* VsT = VsB + kp * 16384;
                #pragma unroll
                for (int kc = 0; kc < 2; ++kc) {
                    v8s pb = *(const v8s*)&Pt[q * 32 + (((kc * 2 + s5) ^ pswz) * 8)];
                    #pragma unroll
                    for (int chb = 0; chb < 8; ++chb) {
                        int ch = chh * 256 + chb * 32 + l31;
                        v8s vf = *(const v8s*)&VsT[ch * 32 +
                                                   (((kc * 2 + s5) ^ ((ch >> 1) & 3)) * 8)];
                        acc[chb] = MFMA32(vf, pb, acc[chb]);
                    }
                }
            }
            __syncthreads();
        }
        __syncthreads();   // wait for lsum
        float inv = 1.0f / (lsum[q] + lsum[64 + q]);
        int token = bz * 1024 + qb * 64 + q;
        #pragma unroll
        for (int chb = 0; chb < 8; ++chb) {
            #pragma unroll
            for (int rg = 0; rg < 4; ++rg) {
                int ch0 = chh * 256 + chb * 32 + rg * 8 + s5 * 4;
                u16 o4[4];
                #pragma unroll
                for (int i = 0; i < 4; ++i) o4[i] = f2bf(acc[chb][rg * 4 + i] * inv);
                *(uint2*)&O[(size_t)token * 512 + ch0] = *(const uint2*)o4;
            }
        }
    }
}

// ---------------------------------------------------------------------------
// Proj GEMM + residual, BK=64, counted-vmcnt double-buffer (round-6) + T1
// XCD swizzle: 4 consecutive batches per XCD (O-panel reuse L2-resident).
// out[b][c][token] = x + Wp @ O_b^T + bp
// ---------------------------------------------------------------------------
__global__ __launch_bounds__(256, 2) void gemm_proj(
    const u16* __restrict__ Wp, const u16* __restrict__ O,
    const float* __restrict__ x, const float* __restrict__ bp,
    float* __restrict__ out) {
    int lin = blockIdx.x + 8 * blockIdx.y + 32 * blockIdx.z;   // hw linear id
    int v = (lin & 7) * 128 + (lin >> 3);                      // bijective (1024 % 8 == 0)
    int n0 = (v & 7) * 128;
    int m0 = ((v >> 3) & 3) * 128;
    int b  = v >> 5;
    __shared__ alignas(16) u16 As[2 * 8192];
    __shared__ alignas(16) u16 Bs[2 * 8192];
    int t = threadIdx.x, w = t >> 6, l = t & 63;
    int lane16 = l & 15, quad = l >> 4;
    int wm = w & 1, wn = w >> 1;
    v4f acc[4][4] = {};

#define STAGE_PRJ(buf, k0)                                                     \
    {                                                                          \
        _Pragma("unroll")                                                      \
        for (int i_ = 0; i_ < 4; ++i_) {                                       \
            int id_ = i_ * 256 + t, row_ = id_ >> 3, c_ = id_ & 7;             \
            int sc_ = c_ ^ (row_ & 7);                                         \
            gl2lds(&Wp[(size_t)(m0 + row_) * 512 + (k0) + sc_ * 8],            \
                   &As[(buf) * 8192 + row_ * 64 + c_ * 8]);                    \
            gl2lds(&O[(size_t)(b * 1024 + n0 + row_) * 512 + (k0) + sc_ * 8],  \
                   &Bs[(buf) * 8192 + row_ * 64 + c_ * 8]);                    \
        }                                                                      \
    }

    STAGE_PRJ(0, 0);
    STAGE_PRJ(1, 64);
    asm volatile("s_waitcnt vmcnt(8)" ::: "memory");
    __builtin_amdgcn_s_barrier();
    __builtin_amdgcn_sched_barrier(0);

    for (int tt = 0; tt < 8; ++tt) {
        int cb = (tt & 1) * 8192;
        #pragma unroll
        for (int hh = 0; hh < 2; ++hh) {
            v8s af[4], bf[4];
            #pragma unroll
            for (int i = 0; i < 4; ++i) {
                int row = wm * 64 + i * 16 + lane16;
                af[i] = *(const v8s*)&As[cb + row * 64 +
                                         (((hh * 4 + quad) ^ (lane16 & 7)) * 8)];
            }
            #pragma unroll
            for (int j = 0; j < 4; ++j) {
                int row = wn * 64 + j * 16 + lane16;
                bf[j] = *(const v8s*)&Bs[cb + row * 64 +
                                         (((hh * 4 + quad) ^ (lane16 & 7)) * 8)];
            }
            #pragma unroll
            for (int i = 0; i < 4; ++i)
                #pragma unroll
                for (int j = 0; j < 4; ++j)
                    acc[i][j] = MFMA16(af[i], bf[j], acc[i][j]);
        }
        __builtin_amdgcn_s_barrier();
        __builtin_amdgcn_sched_barrier(0);
        if (tt + 2 < 8) {
            STAGE_PRJ(tt & 1, (tt + 2) * 64);
            asm volatile("s_waitcnt vmcnt(8)" ::: "memory");
        } else {
            asm volatile("s_waitcnt vmcnt(0)" ::: "memory");
        }
        __builtin_amdgcn_s_barrier();
        __builtin_amdgcn_sched_barrier(0);
    }
#undef STAGE_PRJ

    #pragma unroll
    for (int i = 0; i < 4; ++i) {
        #pragma unroll
        for (int r = 0; r < 4; ++r) {
            int row = wm * 64 + i * 16 + quad * 4 + r;
            float bia = bp[m0 + row];
            #pragma unroll
            for (int j = 0; j < 4; ++j) {
                int col = wn * 64 + j * 16 + lane16;
                size_t idx = (size_t)(b * 512 + m0 + row) * 1024 + n0 + col;
                out[idx] = acc[i][j][r] + bia + x[idx];
            }
        }
    }
}

// ---------------------------------------------------------------------------
extern "C" void kernel_launch(void* const* d_in, const int* in_sizes, int n_in,
                              void* d_out, int out_size, void* d_ws, size_t ws_size,
                              hipStream_t stream) {
    (void)in_sizes; (void)n_in; (void)out_size; (void)ws_size;
    const float* x   = (const float*)d_in[0];
    const float* gnw = (const float*)d_in[1];
    const float* gnb = (const float*)d_in[2];
    const float* wq  = (const float*)d_in[3];
    const float* bq  = (const float*)d_in[4];
    const float* wk  = (const float*)d_in[5];
    const float* bk  = (const float*)d_in[6];
    const float* wv  = (const float*)d_in[7];
    const float* bv  = (const float*)d_in[8];
    const float* wp  = (const float*)d_in[9];
    const float* bp  = (const float*)d_in[10];
    float* out = (float*)d_out;

    char* ws = (char*)d_ws;
    u16*    Wqkv  = (u16*)(ws + 0);                       // 1.5 MB
    u16*    Wp    = (u16*)(ws + 1572864);                 // 0.5 MB
    float*  bqkv  = (float*)(ws + 2097152);               // 6 KB
    float2* stats = (float2*)(ws + 2105344);              // 8 KB
    u16*    h     = (u16*)(ws + 4194304ULL);              // 32 MB (reused as O)
    u16*    Qb    = (u16*)(ws + 4194304ULL + 33554432ULL);        // 32 MB
    u16*    Kb    = (u16*)(ws + 4194304ULL + 2ULL * 33554432ULL); // 32 MB tiled/swizzled
    u16*    Vb    = (u16*)(ws + 4194304ULL + 3ULL * 33554432ULL); // 32 MB tiled/swizzled

    gn_stats<<<dim3(32, 32), 256, 0, stream>>>(x, stats, wq, wk, wv, wp,
                                               bq, bk, bv, Wqkv, Wp, bqkv);
    gn_apply<<<dim3(16, 32), 256, 0, stream>>>(x, stats, gnw, gnb, h);
    gemm_qkv<<<dim3(12, 256), 256, 0, stream>>>(h, Wqkv, bqkv, Qb, Kb, Vb);
    flash_attn<<<512, 512, 0, stream>>>(Qb, Kb, Vb, h /* -> O */);
    gemm_proj<<<dim3(8, 4, 32), 256, 0, stream>>>(Wp, h /* O */, x, bp, out);
}

// Round 10
// 320.055 us; speedup vs baseline: 1.2024x; 1.0102x over previous
//
#include <hip/hip_runtime.h>

typedef unsigned short u16;
typedef unsigned int u32;
typedef short v8s __attribute__((ext_vector_type(8)));
typedef float v4f __attribute__((ext_vector_type(4)));
typedef float v16f __attribute__((ext_vector_type(16)));

#define MFMA16(a, b, c) __builtin_amdgcn_mfma_f32_16x16x32_bf16((a), (b), (c), 0, 0, 0)
#define MFMA32(a, b, c) __builtin_amdgcn_mfma_f32_32x32x16_bf16((a), (b), (c), 0, 0, 0)

static __device__ __forceinline__ u16 f2bf(float f) {
    u32 u = __float_as_uint(f);
    u += 0x7fffu + ((u >> 16) & 1u);   // RNE
    return (u16)(u >> 16);
}

// async global->LDS, 16B per lane. LDS dest must be wave-uniform base + lane*16.
static __device__ __forceinline__ void gl2lds(const u16* g, u16* l) {
    __builtin_amdgcn_global_load_lds(
        (const __attribute__((address_space(1))) void*)g,
        (__attribute__((address_space(3))) void*)l, 16, 0, 0);
}

// ---------------------------------------------------------------------------
// GroupNorm pass 1 + fused weight prep (round-8, banked).
// ---------------------------------------------------------------------------
__global__ __launch_bounds__(256) void gn_stats(
    const float* __restrict__ x, float2* __restrict__ stats,
    const float* __restrict__ wq, const float* __restrict__ wk,
    const float* __restrict__ wv, const float* __restrict__ wp,
    const float* __restrict__ bq, const float* __restrict__ bk,
    const float* __restrict__ bv,
    u16* __restrict__ Wqkv, u16* __restrict__ Wp, float* __restrict__ bqkv) {
    int g = blockIdx.x, b = blockIdx.y;
    int t = threadIdx.x;

    // ---- fused prep ----
    {
        int bid = b * 32 + g;              // 0..1023
        int base = bid * 1024 + t * 4;     // 0..1048572, 4-aligned
        float4 v;
        if (base < 262144)      v = *(const float4*)&wq[base];
        else if (base < 524288) v = *(const float4*)&wk[base - 262144];
        else if (base < 786432) v = *(const float4*)&wv[base - 524288];
        else                    v = *(const float4*)&wp[base - 786432];
        u16 o[4] = { f2bf(v.x), f2bf(v.y), f2bf(v.z), f2bf(v.w) };
        if (base < 786432) *(uint2*)&Wqkv[base] = *(const uint2*)o;
        else               *(uint2*)&Wp[base - 786432] = *(const uint2*)o;
        if (bid == 0 && t < 384) {
            int id0 = t * 4;
            #pragma unroll
            for (int i = 0; i < 4; ++i) {
                int id = id0 + i;
                float bb = (id < 512) ? bq[id]
                         : (id < 1024 ? bk[id - 512] : bv[id - 1024]);
                bqkv[id] = bb;
            }
        }
    }

    // ---- stats ----
    const float4* x4 = (const float4*)x + (size_t)(b * 512 + g * 16) * 256;
    float s = 0.f, s2 = 0.f;
    for (int i = t; i < 4096; i += 256) {
        float4 v = x4[i];
        s  += v.x + v.y + v.z + v.w;
        s2 += v.x * v.x + v.y * v.y + v.z * v.z + v.w * v.w;
    }
    #pragma unroll
    for (int d = 1; d < 64; d <<= 1) { s += __shfl_xor(s, d); s2 += __shfl_xor(s2, d); }
    __shared__ float red1[4], red2[4];
    int w = t >> 6;
    if ((t & 63) == 0) { red1[w] = s; red2[w] = s2; }
    __syncthreads();
    if (t == 0) {
        s = red1[0] + red1[1] + red1[2] + red1[3];
        s2 = red2[0] + red2[1] + red2[2] + red2[3];
        float mu = s * (1.0f / 16384.0f);
        float var = s2 * (1.0f / 16384.0f) - mu * mu;
        stats[b * 32 + g] = make_float2(mu, rsqrtf(var + 1e-5f));
    }
}

// ---------------------------------------------------------------------------
// GroupNorm pass 2 + transpose: x[b,c,s] fp32 -> h[b*1024+s][c] bf16
// (token-major). T1 XCD cluster: v = (lin&7)*64 + lin>>3 puts batches
// 4x..4x+3 on XCD x — h writes (1 MB/batch, 4 MB/XCD = one L2) land in the
// SAME XCD L2 that gemm_qkv's m-panel cluster will read them from.
// ---------------------------------------------------------------------------
__global__ __launch_bounds__(256) void gn_apply(
    const float* __restrict__ x, const float2* __restrict__ stats,
    const float* __restrict__ gnw, const float* __restrict__ gnb,
    u16* __restrict__ h) {
    int lin = blockIdx.x + 16 * blockIdx.y;   // hw linear id
    int v0 = (lin & 7) * 64 + (lin >> 3);     // bijective (512 % 8 == 0)
    int st = v0 & 15, b = v0 >> 4;
    int s0 = st * 64;
    __shared__ float smu[32], srs[32], sw[512], sbv[512];
    __shared__ alignas(16) u16 hs[64][520];
    int t = threadIdx.x;
    if (t < 32) { float2 v = stats[b * 32 + t]; smu[t] = v.x; srs[t] = v.y; }
    sw[t] = gnw[t]; sw[t + 256] = gnw[t + 256];
    sbv[t] = gnb[t]; sbv[t + 256] = gnb[t + 256];
    __syncthreads();
    #pragma unroll 4
    for (int it = 0; it < 32; ++it) {
        int id = it * 256 + t;
        int c = id >> 4, f4 = id & 15;
        float4 v = ((const float4*)x)[(size_t)(b * 512 + c) * 256 + (s0 >> 2) + f4];
        int g = c >> 4;
        float mu = smu[g], r = srs[g], wgt = sw[c], bia = sbv[c];
        hs[f4 * 4 + 0][c] = f2bf((v.x - mu) * r * wgt + bia);
        hs[f4 * 4 + 1][c] = f2bf((v.y - mu) * r * wgt + bia);
        hs[f4 * 4 + 2][c] = f2bf((v.z - mu) * r * wgt + bia);
        hs[f4 * 4 + 3][c] = f2bf((v.w - mu) * r * wgt + bia);
    }
    __syncthreads();
    int lane = t & 63, wrow = t >> 6;
    #pragma unroll 4
    for (int it = 0; it < 16; ++it) {
        int s = it * 4 + wrow;
        float4 vv = *(const float4*)&hs[s][lane * 8];
        *((float4*)h + (size_t)(b * 1024 + s0 + s) * 64 + lane) = vv;
    }
}

// ---------------------------------------------------------------------------
// QKV GEMM, BK=64, counted-vmcnt double-buffer (round-6) + T1 XCD-aware
// block swizzle: virtual id v = (lin&7)*384 + lin>>3 clusters 32 consecutive
// m0-panels x all 12 n0 per XCD -> per-XCD h working set = 4 MB = one L2;
// the 12 same-m0 blocks hit the h panel in L2 instead of re-fetching via L3.
// ---------------------------------------------------------------------------
__global__ __launch_bounds__(256, 2) void gemm_qkv(
    const u16* __restrict__ h, const u16* __restrict__ Wqkv,
    const float* __restrict__ bqkv,
    u16* __restrict__ Qo, u16* __restrict__ Ko, u16* __restrict__ Vo) {
    int lin = blockIdx.x + 12 * blockIdx.y;        // hardware linear id
    int v = (lin & 7) * 384 + (lin >> 3);          // bijective (3072 % 8 == 0)
    int n0 = (v % 12) * 128, m0 = (v / 12) * 128;
    __shared__ alignas(16) char ldsb[65536];
    u16* As = (u16*)ldsb;             // [2][128][64]  32 KB
    u16* Bs = (u16*)(ldsb + 32768);   // [2][128][64]  32 KB
    u16* Tr = (u16*)ldsb;             // [128][136] epilogue overlay
    int t = threadIdx.x, w = t >> 6, l = t & 63;
    int lane16 = l & 15, quad = l >> 4;
    int wm = w & 1, wn = w >> 1;
    v4f acc[4][4] = {};

#define STAGE_QKV(buf, k0)                                                     \
    {                                                                          \
        _Pragma("unroll")                                                      \
        for (int i_ = 0; i_ < 4; ++i_) {                                       \
            int id_ = i_ * 256 + t, row_ = id_ >> 3, c_ = id_ & 7;             \
            int sc_ = c_ ^ (row_ & 7);                                         \
            gl2lds(&h[(size_t)(m0 + row_) * 512 + (k0) + sc_ * 8],             \
                   &As[(buf) * 8192 + row_ * 64 + c_ * 8]);                    \
            gl2lds(&Wqkv[(size_t)(n0 + row_) * 512 + (k0) + sc_ * 8],          \
                   &Bs[(buf) * 8192 + row_ * 64 + c_ * 8]);                    \
        }                                                                      \
    }

    STAGE_QKV(0, 0);
    STAGE_QKV(1, 64);
    asm volatile("s_waitcnt vmcnt(8)" ::: "memory");
    __builtin_amdgcn_s_barrier();
    __builtin_amdgcn_sched_barrier(0);

    for (int tt = 0; tt < 8; ++tt) {
        int cb = (tt & 1) * 8192;
        #pragma unroll
        for (int hh = 0; hh < 2; ++hh) {
            v8s af[4], bf[4];
            #pragma unroll
            for (int i = 0; i < 4; ++i) {
                int row = wm * 64 + i * 16 + lane16;
                af[i] = *(const v8s*)&As[cb + row * 64 +
                                         (((hh * 4 + quad) ^ (lane16 & 7)) * 8)];
            }
            #pragma unroll
            for (int j = 0; j < 4; ++j) {
                int row = wn * 64 + j * 16 + lane16;
                bf[j] = *(const v8s*)&Bs[cb + row * 64 +
                                         (((hh * 4 + quad) ^ (lane16 & 7)) * 8)];
            }
            #pragma unroll
            for (int i = 0; i < 4; ++i)
                #pragma unroll
                for (int j = 0; j < 4; ++j)
                    acc[i][j] = MFMA16(af[i], bf[j], acc[i][j]);
        }
        __builtin_amdgcn_s_barrier();              // all readers of buf done
        __builtin_amdgcn_sched_barrier(0);
        if (tt + 2 < 8) {
            STAGE_QKV(tt & 1, (tt + 2) * 64);      // refill freed buffer
            asm volatile("s_waitcnt vmcnt(8)" ::: "memory");   // L(t+1) landed
        } else {
            asm volatile("s_waitcnt vmcnt(0)" ::: "memory");   // tail drain
        }
        __builtin_amdgcn_s_barrier();              // everyone's next buf ready
        __builtin_amdgcn_sched_barrier(0);
    }
#undef STAGE_QKV

    float bias[4];
    #pragma unroll
    for (int j = 0; j < 4; ++j) bias[j] = bqkv[n0 + wn * 64 + j * 16 + lane16];

    if (n0 < 1024) {
        // Q or K: stage [token][channel] tile in LDS (Tr overlays As/Bs)
        const float qscale = (n0 < 512) ? 0.04419417382415922f : 1.0f;
        #pragma unroll
        for (int i = 0; i < 4; ++i)
            #pragma unroll
            for (int j = 0; j < 4; ++j)
                #pragma unroll
                for (int r = 0; r < 4; ++r) {
                    int row = wm * 64 + i * 16 + quad * 4 + r;
                    int col = wn * 64 + j * 16 + lane16;
                    Tr[row * 136 + col] = f2bf((acc[i][j][r] + bias[j]) * qscale);
                }
        __syncthreads();
        if (n0 < 512) {
            #pragma unroll
            for (int it = 0; it < 8; ++it) {
                int id = it * 256 + t, row = id >> 4, ch = id & 15;
                *(float4*)&Qo[(size_t)(m0 + row) * 512 + n0 + ch * 8] =
                    *(const float4*)&Tr[row * 136 + ch * 8];
            }
        } else {
            int c0 = n0 - 512, b = m0 >> 10, sb = m0 & 1023;
            #pragma unroll
            for (int it = 0; it < 8; ++it) {
                int id = it * 256 + t, row = id >> 4, ch = id & 15;
                int s = sb + row, kt = s >> 5, key = s & 31;
                int kb = ((c0 + ch * 8) >> 3) ^ (key & 7);   // XOR swizzle (64 blocks/row)
                *(float4*)&Ko[((size_t)(b * 32 + kt)) * 16384 + key * 512 + kb * 8] =
                    *(const float4*)&Tr[row * 136 + ch * 8];
            }
        }
    } else {
        // V: stage TRANSPOSED [channel][token] in LDS
        #pragma unroll
        for (int i = 0; i < 4; ++i)
            #pragma unroll
            for (int j = 0; j < 4; ++j)
                #pragma unroll
                for (int r = 0; r < 4; ++r) {
                    int row = wm * 64 + i * 16 + quad * 4 + r;
                    int col = wn * 64 + j * 16 + lane16;
                    Tr[col * 136 + row] = f2bf(acc[i][j][r] + bias[j]);
                }
        __syncthreads();
        int c0 = n0 - 1024, b = m0 >> 10, sb = m0 & 1023;
        #pragma unroll
        for (int it = 0; it < 8; ++it) {
            int id = it * 256 + t, c = id >> 4, ch8 = id & 15;
            int key0 = sb + ch8 * 8;                  // 8 consecutive keys
            int kt = key0 >> 5;
            int kblk = (key0 >> 3) & 3;               // block within 4-block row
            int ch = c0 + c;
            int swz = (ch >> 1) & 3;
            *(float4*)&Vo[((size_t)(b * 32 + kt)) * 16384 + (size_t)ch * 32 +
                          ((kblk ^ swz) * 8)] =
                *(const float4*)&Tr[c * 136 + ch8 * 8];
        }
    }
}

// ---------------------------------------------------------------------------
// Flash attention v3 (the proven 102.6-106.3 µs kernel, unchanged).
// ---------------------------------------------------------------------------
__global__ __launch_bounds__(512, 2) void flash_attn(
    const u16* __restrict__ Q, const u16* __restrict__ Kt,
    const u16* __restrict__ Vt, u16* __restrict__ O) {
    int idx = blockIdx.x;
    int xcd = idx & 7, j = idx >> 3;          // XCD-aware: 4 batches per XCD
    int bz = xcd * 4 + (j >> 4);
    int qb = j & 15;                          // 64-query block

    __shared__ alignas(16) char lds[139776];
    u16*   KsB  = (u16*)lds;                  // [2][32][512]  64 KB
    u16*   VsB  = (u16*)(lds + 65536);        // [2][512][32]  64 KB
    u16*   Pb   = (u16*)(lds + 131072);       // [2][64][32]    8 KB
    float* lsum = (float*)(lds + 139264);     // [2][64]      0.5 KB

    int t = threadIdx.x, w = t >> 6, l = t & 63;
    int lane16 = l & 15, quad = l >> 4;
    int s5 = l >> 5, l31 = l & 31;

    const u16* Kb = Kt + (size_t)bz * 32 * 16384;
    const u16* Vb = Vt + (size_t)bz * 32 * 16384;

    // prologue: stage K tile 0 (each wave copies 4 KB of the 32 KB tile)
    #pragma unroll
    for (int c = 0; c < 4; ++c) {
        int ch = w * 4 + c;
        gl2lds(&Kb[ch * 512 + l * 8], &KsB[ch * 512 + l * 8]);
    }
    __syncthreads();

    if (w < 4) {
        // ================= PRODUCER =================
        int qs = w & 1, kh = w >> 1;
        int qrow = bz * 1024 + qb * 64 + qs * 32 + lane16;
        v8s qf0[16], qf1[16];
        #pragma unroll
        for (int kk = 0; kk < 16; ++kk) {
            qf0[kk] = *(const v8s*)&Q[(size_t)qrow * 512 + kk * 32 + quad * 8];
            qf1[kk] = *(const v8s*)&Q[(size_t)(qrow + 16) * 512 + kk * 32 + quad * 8];
        }
        v4f li0 = {}, li1 = {};
        int key = kh * 16 + lane16;
        int krowoff = key * 512;
        int kswz = lane16 & 7;

        for (int kt = 0; kt <= 32; ++kt) {
            if (kt + 1 < 32) {
                u16* kd = KsB + ((kt + 1) & 1) * 16384;
                const u16* ks = Kb + (size_t)(kt + 1) * 16384;
                #pragma unroll
                for (int c = 0; c < 4; ++c) {
                    int ch = w * 4 + c;
                    gl2lds(&ks[ch * 512 + l * 8], &kd[ch * 512 + l * 8]);
                }
            }
            if (kt < 32) {
                u16* vd = VsB + (kt & 1) * 16384;
                const u16* vs = Vb + (size_t)kt * 16384;
                #pragma unroll
                for (int c = 0; c < 4; ++c) {
                    int ch = w * 4 + c;
                    gl2lds(&vs[ch * 512 + l * 8], &vd[ch * 512 + l * 8]);
                }
                const u16* KsT = KsB + (kt & 1) * 16384;
                u16* Pt = Pb + (kt & 1) * 2048;
                v4f sA = {}, sB = {};
                #pragma unroll
                for (int kk = 0; kk < 16; ++kk) {
                    v8s b = *(const v8s*)&KsT[krowoff + (((kk * 4 + quad) ^ kswz) * 8)];
                    sA = MFMA16(qf0[kk], b, sA);
                    sB = MFMA16(qf1[kk], b, sB);
                }
                #pragma unroll
                for (int r = 0; r < 4; ++r) {
                    float p0 = __expf(sA[r]), p1 = __expf(sB[r]);
                    li0[r] += p0; li1[r] += p1;
                    int q0 = qs * 32 + quad * 4 + r, q1 = q0 + 16;
                    Pt[q0 * 32 + (((key >> 3) ^ ((q0 >> 1) & 3)) * 8) + (key & 7)] = f2bf(p0);
                    Pt[q1 * 32 + (((key >> 3) ^ ((q1 >> 1) & 3)) * 8) + (key & 7)] = f2bf(p1);
                }
            }
            __syncthreads();
        }
        // reduce l over the 16 keys of this wave, publish per-kh partials
        #pragma unroll
        for (int r = 0; r < 4; ++r) {
            float a = li0[r], b = li1[r];
            a += __shfl_xor(a, 1); a += __shfl_xor(a, 2);
            a += __shfl_xor(a, 4); a += __shfl_xor(a, 8);
            b += __shfl_xor(b, 1); b += __shfl_xor(b, 2);
            b += __shfl_xor(b, 4); b += __shfl_xor(b, 8);
            if (lane16 == 0) {
                lsum[kh * 64 + qs * 32 + quad * 4 + r] = a;
                lsum[kh * 64 + qs * 32 + 16 + quad * 4 + r] = b;
            }
        }
        __syncthreads();
    } else {
        // ================= CONSUMER =================
        int cw = w - 4, qs2 = cw & 1, chh = cw >> 1;
        v16f acc[8] = {};
        int q = qs2 * 32 + l31;
        int pswz = (q >> 1) & 3;

        for (int kt = 0; kt <= 32; ++kt) {
            if (kt + 1 < 32) {
                u16* kd = KsB + ((kt + 1) & 1) * 16384;
                const u16* ks = Kb + (size_t)(kt + 1) * 16384;
                #pragma unroll
                for (int c = 0; c < 4; ++c) {
                    int ch = w * 4 + c;
                    gl2lds(&ks[ch * 512 + l * 8], &kd[ch * 512 + l * 8]);
                }
            }
            if (kt < 32) {
                u16* vd = VsB + (kt & 1) * 16384;
                const u16* vs = Vb + (size_t)kt * 16384;
                #pragma unroll
                for (int c = 0; c < 4; ++c) {
                    int ch = w * 4 + c;
                    gl2lds(&vs[ch * 512 + l * 8], &vd[ch * 512 + l * 8]);
                }
            }
            if (kt >= 1) {
                int kp = (kt - 1) & 1;
                const u16* Pt  = Pb + kp * 2048;
                const u16* VsT = VsB + kp * 16384;
                #pragma unroll
                for (int kc = 0; kc < 2; ++kc) {
                    v8s pb = *(const v8s*)&Pt[q * 32 + (((kc * 2 + s5) ^ pswz) * 8)];
                    #pragma unroll
                    for (int chb = 0; chb < 8; ++chb) {
                        int ch = chh * 256 + chb * 32 + l31;
                        v8s vf = *(const v8s*)&VsT[ch * 32 +
                                                   (((kc * 2 + s5) ^ ((ch >> 1) & 3)) * 8)];
                        acc[chb] = MFMA32(vf, pb, acc[chb]);
                    }
                }
            }
            __syncthreads();
        }
        __syncthreads();   // wait for lsum
        float inv = 1.0f / (lsum[q] + lsum[64 + q]);
        int token = bz * 1024 + qb * 64 + q;
        #pragma unroll
        for (int chb = 0; chb < 8; ++chb) {
            #pragma unroll
            for (int rg = 0; rg < 4; ++rg) {
                int ch0 = chh * 256 + chb * 32 + rg * 8 + s5 * 4;
                u16 o4[4];
                #pragma unroll
                for (int i = 0; i < 4; ++i) o4[i] = f2bf(acc[chb][rg * 4 + i] * inv);
                *(uint2*)&O[(size_t)token * 512 + ch0] = *(const uint2*)o4;
            }
        }
    }
}

// ---------------------------------------------------------------------------
// Proj GEMM + residual, BK=64, counted-vmcnt double-buffer (round-6) + T1
// XCD swizzle: 4 consecutive batches per XCD (O-panel reuse L2-resident).
// out[b][c][token] = x + Wp @ O_b^T + bp
// ---------------------------------------------------------------------------
__global__ __launch_bounds__(256, 2) void gemm_proj(
    const u16* __restrict__ Wp, const u16* __restrict__ O,
    const float* __restrict__ x, const float* __restrict__ bp,
    float* __restrict__ out) {
    int lin = blockIdx.x + 8 * blockIdx.y + 32 * blockIdx.z;   // hw linear id
    int v = (lin & 7) * 128 + (lin >> 3);                      // bijective (1024 % 8 == 0)
    int n0 = (v & 7) * 128;
    int m0 = ((v >> 3) & 3) * 128;
    int b  = v >> 5;
    __shared__ alignas(16) u16 As[2 * 8192];
    __shared__ alignas(16) u16 Bs[2 * 8192];
    int t = threadIdx.x, w = t >> 6, l = t & 63;
    int lane16 = l & 15, quad = l >> 4;
    int wm = w & 1, wn = w >> 1;
    v4f acc[4][4] = {};

#define STAGE_PRJ(buf, k0)                                                     \
    {                                                                          \
        _Pragma("unroll")                                                      \
        for (int i_ = 0; i_ < 4; ++i_) {                                       \
            int id_ = i_ * 256 + t, row_ = id_ >> 3, c_ = id_ & 7;             \
            int sc_ = c_ ^ (row_ & 7);                                         \
            gl2lds(&Wp[(size_t)(m0 + row_) * 512 + (k0) + sc_ * 8],            \
                   &As[(buf) * 8192 + row_ * 64 + c_ * 8]);                    \
            gl2lds(&O[(size_t)(b * 1024 + n0 + row_) * 512 + (k0) + sc_ * 8],  \
                   &Bs[(buf) * 8192 + row_ * 64 + c_ * 8]);                    \
        }                                                                      \
    }

    STAGE_PRJ(0, 0);
    STAGE_PRJ(1, 64);
    asm volatile("s_waitcnt vmcnt(8)" ::: "memory");
    __builtin_amdgcn_s_barrier();
    __builtin_amdgcn_sched_barrier(0);

    for (int tt = 0; tt < 8; ++tt) {
        int cb = (tt & 1) * 8192;
        #pragma unroll
        for (int hh = 0; hh < 2; ++hh) {
            v8s af[4], bf[4];
            #pragma unroll
            for (int i = 0; i < 4; ++i) {
                int row = wm * 64 + i * 16 + lane16;
                af[i] = *(const v8s*)&As[cb + row * 64 +
                                         (((hh * 4 + quad) ^ (lane16 & 7)) * 8)];
            }
            #pragma unroll
            for (int j = 0; j < 4; ++j) {
                int row = wn * 64 + j * 16 + lane16;
                bf[j] = *(const v8s*)&Bs[cb + row * 64 +
                                         (((hh * 4 + quad) ^ (lane16 & 7)) * 8)];
            }
            #pragma unroll
            for (int i = 0; i < 4; ++i)
                #pragma unroll
                for (int j = 0; j < 4; ++j)
                    acc[i][j] = MFMA16(af[i], bf[j], acc[i][j]);
        }
        __builtin_amdgcn_s_barrier();
        __builtin_amdgcn_sched_barrier(0);
        if (tt + 2 < 8) {
            STAGE_PRJ(tt & 1, (tt + 2) * 64);
            asm volatile("s_waitcnt vmcnt(8)" ::: "memory");
        } else {
            asm volatile("s_waitcnt vmcnt(0)" ::: "memory");
        }
        __builtin_amdgcn_s_barrier();
        __builtin_amdgcn_sched_barrier(0);
    }
#undef STAGE_PRJ

    #pragma unroll
    for (int i = 0; i < 4; ++i) {
        #pragma unroll
        for (int r = 0; r < 4; ++r) {
            int row = wm * 64 + i * 16 + quad * 4 + r;
            float bia = bp[m0 + row];
            #pragma unroll
            for (int j = 0; j < 4; ++j) {
                int col = wn * 64 + j * 16 + lane16;
                size_t idx = (size_t)(b * 512 + m0 + row) * 1024 + n0 + col;
                out[idx] = acc[i][j][r] + bia + x[idx];
            }
        }
    }
}

// ---------------------------------------------------------------------------
extern "C" void kernel_launch(void* const* d_in, const int* in_sizes, int n_in,
                              void* d_out, int out_size, void* d_ws, size_t ws_size,
                              hipStream_t stream) {
    (void)in_sizes; (void)n_in; (void)out_size; (void)ws_size;
    const float* x   = (const float*)d_in[0];
    const float* gnw = (const float*)d_in[1];
    const float* gnb = (const float*)d_in[2];
    const float* wq  = (const float*)d_in[3];
    const float* bq  = (const float*)d_in[4];
    const float* wk  = (const float*)d_in[5];
    const float* bk  = (const float*)d_in[6];
    const float* wv  = (const float*)d_in[7];
    const float* bv  = (const float*)d_in[8];
    const float* wp  = (const float*)d_in[9];
    const float* bp  = (const float*)d_in[10];
    float* out = (float*)d_out;

    char* ws = (char*)d_ws;
    u16*    Wqkv  = (u16*)(ws + 0);                       // 1.5 MB
    u16*    Wp    = (u16*)(ws + 1572864);                 // 0.5 MB
    float*  bqkv  = (float*)(ws + 2097152);               // 6 KB
    float2* stats = (float2*)(ws + 2105344);              // 8 KB
    u16*    h     = (u16*)(ws + 4194304ULL);              // 32 MB (reused as O)
    u16*    Qb    = (u16*)(ws + 4194304ULL + 33554432ULL);        // 32 MB
    u16*    Kb    = (u16*)(ws + 4194304ULL + 2ULL * 33554432ULL); // 32 MB tiled/swizzled
    u16*    Vb    = (u16*)(ws + 4194304ULL + 3ULL * 33554432ULL); // 32 MB tiled/swizzled

    gn_stats<<<dim3(32, 32), 256, 0, stream>>>(x, stats, wq, wk, wv, wp,
                                               bq, bk, bv, Wqkv, Wp, bqkv);
    gn_apply<<<dim3(16, 32), 256, 0, stream>>>(x, stats, gnw, gnb, h);
    gemm_qkv<<<dim3(12, 256), 256, 0, stream>>>(h, Wqkv, bqkv, Qb, Kb, Vb);
    flash_attn<<<512, 512, 0, stream>>>(Qb, Kb, Vb, h /* -> O */);
    gemm_proj<<<dim3(8, 4, 32), 256, 0, stream>>>(Wp, h /* O */, x, bp, out);
}